// Round 3
// baseline (485.454 us; speedup 1.0000x reference)
//
#include <hip/hip_runtime.h>

#define IN_NODE 128
#define OUT_NODE 64
#define OUT_EDGE 16
#define NHEAD 4
#define HN (NHEAD * OUT_NODE)  // 256
#define HE (NHEAD * OUT_EDGE)  // 64
#define LEAKY 0.01f
#define CAP 192                // cached slots per wave in fused aggregate

__device__ __forceinline__ float bf2f(unsigned short u) {
    union { unsigned u; float f; } v; v.u = ((unsigned)u) << 16; return v.f;
}
__device__ __forceinline__ unsigned short f2bf(float x) {
    union { float f; unsigned u; } v; v.f = x;
    unsigned r = v.u + 0x7FFF + ((v.u >> 16) & 1);   // RNE
    return (unsigned short)(r >> 16);
}

// ---------------- wsum[k] = sum_c W_fij[c][k]  (16x64 -> 64) ----------------
__global__ void prep_wsum(const float* __restrict__ W_fij, float* __restrict__ wsum) {
    int k = threadIdx.x;  // 64 threads
    float s = 0.f;
#pragma unroll
    for (int c = 0; c < 16; ++c) s += W_fij[c * 64 + k];
    wsum[k] = s;
}

// ---------------- C[M,N](bf16) = A[M,128] @ W[128,N] (+bias) ----------------
__global__ __launch_bounds__(256) void gemm_k128(
    const float* __restrict__ A, const float* __restrict__ W,
    const float* __restrict__ bias, unsigned short* __restrict__ C, int M, int N)
{
    __shared__ float At[64 * 68];   // [k][row]
    __shared__ float Ws[64 * 64];   // [k][col]
    const int t = threadIdx.x;
    const int rowBase = blockIdx.x * 64;
    const int colBase = blockIdx.y * 64;
    const int tr = (t >> 4) << 2;
    const int tc = (t & 15) << 2;
    float acc[4][4] = {};

    for (int kt = 0; kt < 128; kt += 64) {
#pragma unroll
        for (int i = 0; i < 4; ++i) {           // stage A transposed
            int f4 = t + i * 256;
            int r = f4 >> 4;
            int kf = (f4 & 15) << 2;
            float4 v = {0.f, 0.f, 0.f, 0.f};
            int row = rowBase + r;
            if (row < M) v = *reinterpret_cast<const float4*>(A + (size_t)row * 128 + kt + kf);
            At[(kf + 0) * 68 + r] = v.x;
            At[(kf + 1) * 68 + r] = v.y;
            At[(kf + 2) * 68 + r] = v.z;
            At[(kf + 3) * 68 + r] = v.w;
        }
#pragma unroll
        for (int i = 0; i < 4; ++i) {           // stage W
            int f4 = t + i * 256;
            int k = f4 >> 4;
            int cf = (f4 & 15) << 2;
            float4 v = *reinterpret_cast<const float4*>(W + (size_t)(kt + k) * N + colBase + cf);
            *reinterpret_cast<float4*>(Ws + k * 64 + cf) = v;
        }
        __syncthreads();
#pragma unroll 8
        for (int k = 0; k < 64; ++k) {
            float4 b = *reinterpret_cast<const float4*>(Ws + k * 64 + tc);
            float4 a = *reinterpret_cast<const float4*>(At + k * 68 + tr);
            acc[0][0] = fmaf(a.x, b.x, acc[0][0]);
            acc[0][1] = fmaf(a.x, b.y, acc[0][1]);
            acc[0][2] = fmaf(a.x, b.z, acc[0][2]);
            acc[0][3] = fmaf(a.x, b.w, acc[0][3]);
            acc[1][0] = fmaf(a.y, b.x, acc[1][0]);
            acc[1][1] = fmaf(a.y, b.y, acc[1][1]);
            acc[1][2] = fmaf(a.y, b.z, acc[1][2]);
            acc[1][3] = fmaf(a.y, b.w, acc[1][3]);
            acc[2][0] = fmaf(a.z, b.x, acc[2][0]);
            acc[2][1] = fmaf(a.z, b.y, acc[2][1]);
            acc[2][2] = fmaf(a.z, b.z, acc[2][2]);
            acc[2][3] = fmaf(a.z, b.w, acc[2][3]);
            acc[3][0] = fmaf(a.w, b.x, acc[3][0]);
            acc[3][1] = fmaf(a.w, b.y, acc[3][1]);
            acc[3][2] = fmaf(a.w, b.z, acc[3][2]);
            acc[3][3] = fmaf(a.w, b.w, acc[3][3]);
        }
        __syncthreads();
    }

    float4 bv = {0.f, 0.f, 0.f, 0.f};
    if (bias) bv = *reinterpret_cast<const float4*>(bias + colBase + tc);
#pragma unroll
    for (int i = 0; i < 4; ++i) {
        int row = rowBase + tr + i;
        if (row < M) {
            ushort4 o = { f2bf(acc[i][0] + bv.x), f2bf(acc[i][1] + bv.y),
                          f2bf(acc[i][2] + bv.z), f2bf(acc[i][3] + bv.w) };
            *reinterpret_cast<ushort4*>(C + (size_t)row * N + colBase + tc) = o;
        }
    }
}

// ---------------- counting sort by dst: hist / scan / scatter(perm) ---------
__global__ void hist_kernel(const int* __restrict__ dst, int* __restrict__ cnt, int E) {
    int i = blockIdx.x * 256 + threadIdx.x;
    if (i < E) atomicAdd(&cnt[dst[i]], 1);
}

__global__ __launch_bounds__(256) void scan1(const int* __restrict__ cnt,
                                             int* __restrict__ row_ptr,
                                             int* __restrict__ partials, int n) {
    __shared__ int sums[256];
    int tid = threadIdx.x;
    int base = blockIdx.x * 1024;
    int v[4]; int tsum = 0;
#pragma unroll
    for (int j = 0; j < 4; ++j) {
        int idx = base + tid * 4 + j;
        v[j] = (idx < n) ? cnt[idx] : 0;
        tsum += v[j];
    }
    sums[tid] = tsum;
    __syncthreads();
    for (int off = 1; off < 256; off <<= 1) {
        int x = (tid >= off) ? sums[tid - off] : 0;
        __syncthreads();
        sums[tid] += x;
        __syncthreads();
    }
    int run = sums[tid] - tsum;
#pragma unroll
    for (int j = 0; j < 4; ++j) {
        int idx = base + tid * 4 + j;
        if (idx < n) row_ptr[idx] = run;
        run += v[j];
    }
    if (tid == 255) partials[blockIdx.x] = sums[255];
}

__global__ __launch_bounds__(256) void scan2(int* __restrict__ partials, int nb) {
    __shared__ int s[256];
    int tid = threadIdx.x;
    int orig = (tid < nb) ? partials[tid] : 0;
    s[tid] = orig;
    __syncthreads();
    for (int off = 1; off < 256; off <<= 1) {
        int x = (tid >= off) ? s[tid - off] : 0;
        __syncthreads();
        s[tid] += x;
        __syncthreads();
    }
    if (tid < nb) partials[tid] = s[tid] - orig;
}

__global__ void scan3(int* __restrict__ row_ptr, const int* __restrict__ partials,
                      int n, int E) {
    int i = blockIdx.x * 256 + threadIdx.x;
    if (i < n) row_ptr[i] += partials[i >> 10];
    if (i == 0) row_ptr[n] = E;
}

__global__ void scatter_kernel(const int* __restrict__ dst,
                               const int* __restrict__ row_ptr, int* __restrict__ cursor,
                               int* __restrict__ perm, int E) {
    int i = blockIdx.x * 256 + threadIdx.x;
    if (i >= E) return;
    int d = dst[i];
    int pos = row_ptr[d] + atomicAdd(&cursor[d], 1);
    perm[pos] = i;
}

// ---------------- fused logits + softmax + aggregation ----------------------
// One wave per dst node. lane = h*16+g.
// Pass 1 (lane=edge-feature h*16+f): logits -> exp -> denominator; cache
// (exp[4], sn) per slot in LDS. Pass 2: weighted h_src gather + head mean.
__global__ __launch_bounds__(256) void fused_aggregate(
    const unsigned short* __restrict__ f_ni, const unsigned short* __restrict__ f_nj,
    const unsigned short* __restrict__ h_src,
    const int* __restrict__ src, const float* __restrict__ reward,
    const int* __restrict__ perm, const int* __restrict__ row_ptr,
    const float* __restrict__ wsum_g, const float* __restrict__ b_e,
    const float* __restrict__ attn,
    float* __restrict__ out, int Nd)
{
    __shared__ float s_exp[4][CAP][4];
    __shared__ int   s_sn[4][CAP];
    int wv = threadIdx.x >> 6;
    int lane = threadIdx.x & 63;
    int d = blockIdx.x * 4 + wv;
    if (d >= Nd) return;
    int beg = row_ptr[d], end = row_ptr[d + 1];

    float fnj = bf2f(f_nj[(size_t)d * HE + lane]);
    float ws = wsum_g[lane], be = b_e[lane], at = attn[lane];

    float den = 0.f;
    for (int slot = beg; slot < end; ++slot) {
        int eid = perm[slot];
        int sn = src[eid];
        float r = reward[eid];
        float v = bf2f(f_ni[(size_t)sn * HE + lane]) + fnj + r * ws + be;
        v = (v >= 0.f) ? v : LEAKY * v;
        float t = v * at;
        t += __shfl_xor(t, 1);
        t += __shfl_xor(t, 2);
        t += __shfl_xor(t, 4);
        t += __shfl_xor(t, 8);     // all lanes in 16-group hold head sum
        float ev = __expf(t);
        den += ev;                 // per-lane == per-head denominator
        int idx = slot - beg;
        if (idx < CAP) {
            if ((lane & 15) == 0) s_exp[wv][idx][lane >> 4] = ev;
            if (lane == 0) s_sn[wv][idx] = sn;
        }
    }
    float inv = (den > 0.f) ? 1.f / den : 0.f;

    int h = lane >> 4;
    float a0 = 0.f, a1 = 0.f, a2 = 0.f, a3 = 0.f;
    for (int slot = beg; slot < end; ++slot) {
        int idx = slot - beg;
        int sn; float ev;
        if (idx < CAP) {           // wave-uniform branch
            sn = s_sn[wv][idx];
            ev = s_exp[wv][idx][h];
        } else {                   // rare overflow: recompute
            int eid = perm[slot];
            sn = src[eid];
            float r = reward[eid];
            float v = bf2f(f_ni[(size_t)sn * HE + lane]) + fnj + r * ws + be;
            v = (v >= 0.f) ? v : LEAKY * v;
            float t = v * at;
            t += __shfl_xor(t, 1);
            t += __shfl_xor(t, 2);
            t += __shfl_xor(t, 4);
            t += __shfl_xor(t, 8);
            ev = __expf(t);
        }
        float w = ev * inv;
        ushort4 u = *reinterpret_cast<const ushort4*>(h_src + (size_t)sn * HN + lane * 4);
        a0 = fmaf(w, bf2f(u.x), a0);
        a1 = fmaf(w, bf2f(u.y), a1);
        a2 = fmaf(w, bf2f(u.z), a2);
        a3 = fmaf(w, bf2f(u.w), a3);
    }
    a0 += __shfl_xor(a0, 16); a0 += __shfl_xor(a0, 32);
    a1 += __shfl_xor(a1, 16); a1 += __shfl_xor(a1, 32);
    a2 += __shfl_xor(a2, 16); a2 += __shfl_xor(a2, 32);
    a3 += __shfl_xor(a3, 16); a3 += __shfl_xor(a3, 32);
    if (lane < 16) {
        float4 o = { fmaxf(a0 * 0.25f, 0.f), fmaxf(a1 * 0.25f, 0.f),
                     fmaxf(a2 * 0.25f, 0.f), fmaxf(a3 * 0.25f, 0.f) };
        *reinterpret_cast<float4*>(out + (size_t)d * OUT_NODE + lane * 4) = o;
    }
}

static inline char* align256(char* p) {
    return (char*)(((uintptr_t)p + 255) & ~(uintptr_t)255);
}

extern "C" void kernel_launch(void* const* d_in, const int* in_sizes, int n_in,
                              void* d_out, int out_size, void* d_ws, size_t ws_size,
                              hipStream_t stream) {
    const float* nfeats    = (const float*)d_in[0];
    const float* dst_feats = (const float*)d_in[1];
    const float* reward    = (const float*)d_in[2];
    const int*   src       = (const int*)d_in[3];
    const int*   dst       = (const int*)d_in[4];
    const float* W_ns      = (const float*)d_in[5];
    const float* b_ns      = (const float*)d_in[6];
    const float* W_ni      = (const float*)d_in[7];
    const float* W_nj      = (const float*)d_in[8];
    const float* W_fij     = (const float*)d_in[9];
    const float* attn      = (const float*)d_in[10];
    const float* b_e       = (const float*)d_in[11];
    float* out = (float*)d_out;

    const int Ns = in_sizes[0] / IN_NODE;
    const int Nd = in_sizes[1] / IN_NODE;
    const int E  = in_sizes[2];

    char* ws = (char*)d_ws;
    unsigned short* f_ni  = (unsigned short*)ws; ws = align256(ws + (size_t)Ns * HE * 2);
    unsigned short* f_nj  = (unsigned short*)ws; ws = align256(ws + (size_t)Nd * HE * 2);
    unsigned short* h_src = (unsigned short*)ws; ws = align256(ws + (size_t)Ns * HN * 2);
    float* wsum    = (float*)ws; ws = align256(ws + HE * 4);
    int*   cnt     = (int*)ws;   ws = align256(ws + (size_t)Nd * 4);
    int*   row_ptr = (int*)ws;   ws = align256(ws + (size_t)(Nd + 1) * 4);
    int*   cursor  = (int*)ws;   ws = align256(ws + (size_t)Nd * 4);
    int*   partials= (int*)ws;   ws = align256(ws + 256 * 4);
    int*   perm    = (int*)ws;   ws = align256(ws + (size_t)E * 4);

    hipMemsetAsync(cnt, 0, (size_t)Nd * 4, stream);
    hipMemsetAsync(cursor, 0, (size_t)Nd * 4, stream);

    prep_wsum<<<1, 64, 0, stream>>>(W_fij, wsum);

    dim3 blk(256);
    gemm_k128<<<dim3((Ns + 63) / 64, 1), blk, 0, stream>>>(nfeats,    W_ni, nullptr, f_ni, Ns, HE);
    gemm_k128<<<dim3((Nd + 63) / 64, 1), blk, 0, stream>>>(dst_feats, W_nj, nullptr, f_nj, Nd, HE);
    gemm_k128<<<dim3((Ns + 63) / 64, 4), blk, 0, stream>>>(nfeats,    W_ns, b_ns,    h_src, Ns, HN);

    hist_kernel<<<(E + 255) / 256, 256, 0, stream>>>(dst, cnt, E);
    int nb = (Nd + 1023) / 1024;
    scan1<<<nb, 256, 0, stream>>>(cnt, row_ptr, partials, Nd);
    scan2<<<1, 256, 0, stream>>>(partials, nb);
    scan3<<<(Nd + 255) / 256, 256, 0, stream>>>(row_ptr, partials, Nd, E);
    scatter_kernel<<<(E + 255) / 256, 256, 0, stream>>>(dst, row_ptr, cursor, perm, E);

    fused_aggregate<<<(Nd + 3) / 4, 256, 0, stream>>>(
        f_ni, f_nj, h_src, src, reward, perm, row_ptr, wsum, b_e, attn, out, Nd);
}

// Round 4
// 403.328 us; speedup vs baseline: 1.2036x; 1.2036x over previous
//
#include <hip/hip_runtime.h>

#define IN_NODE 128
#define OUT_NODE 64
#define OUT_EDGE 16
#define NHEAD 4
#define HN (NHEAD * OUT_NODE)  // 256
#define HE (NHEAD * OUT_EDGE)  // 64
#define LEAKY 0.01f

__device__ __forceinline__ float bf2f(unsigned short u) {
    union { unsigned u; float f; } v; v.u = ((unsigned)u) << 16; return v.f;
}
__device__ __forceinline__ unsigned short f2bf(float x) {
    union { float f; unsigned u; } v; v.f = x;
    unsigned r = v.u + 0x7FFF + ((v.u >> 16) & 1);   // RNE
    return (unsigned short)(r >> 16);
}

// ---------------- wsum[k] = sum_c W_fij[c][k]  (16x64 -> 64) ----------------
__global__ void prep_wsum(const float* __restrict__ W_fij, float* __restrict__ wsum) {
    int k = threadIdx.x;
    float s = 0.f;
#pragma unroll
    for (int c = 0; c < 16; ++c) s += W_fij[c * 64 + k];
    wsum[k] = s;
}

// ---------------- C[M,N](bf16) = A[M,128] @ W[128,N] (+bias) ----------------
__global__ __launch_bounds__(256) void gemm_k128(
    const float* __restrict__ A, const float* __restrict__ W,
    const float* __restrict__ bias, unsigned short* __restrict__ C, int M, int N)
{
    __shared__ float At[64 * 68];   // [k][row]
    __shared__ float Ws[64 * 64];   // [k][col]
    const int t = threadIdx.x;
    const int rowBase = blockIdx.x * 64;
    const int colBase = blockIdx.y * 64;
    const int tr = (t >> 4) << 2;
    const int tc = (t & 15) << 2;
    float acc[4][4] = {};

    for (int kt = 0; kt < 128; kt += 64) {
#pragma unroll
        for (int i = 0; i < 4; ++i) {           // stage A transposed
            int f4 = t + i * 256;
            int r = f4 >> 4;
            int kf = (f4 & 15) << 2;
            float4 v = {0.f, 0.f, 0.f, 0.f};
            int row = rowBase + r;
            if (row < M) v = *reinterpret_cast<const float4*>(A + (size_t)row * 128 + kt + kf);
            At[(kf + 0) * 68 + r] = v.x;
            At[(kf + 1) * 68 + r] = v.y;
            At[(kf + 2) * 68 + r] = v.z;
            At[(kf + 3) * 68 + r] = v.w;
        }
#pragma unroll
        for (int i = 0; i < 4; ++i) {           // stage W
            int f4 = t + i * 256;
            int k = f4 >> 4;
            int cf = (f4 & 15) << 2;
            float4 v = *reinterpret_cast<const float4*>(W + (size_t)(kt + k) * N + colBase + cf);
            *reinterpret_cast<float4*>(Ws + k * 64 + cf) = v;
        }
        __syncthreads();
#pragma unroll 8
        for (int k = 0; k < 64; ++k) {
            float4 b = *reinterpret_cast<const float4*>(Ws + k * 64 + tc);
            float4 a = *reinterpret_cast<const float4*>(At + k * 68 + tr);
            acc[0][0] = fmaf(a.x, b.x, acc[0][0]);
            acc[0][1] = fmaf(a.x, b.y, acc[0][1]);
            acc[0][2] = fmaf(a.x, b.z, acc[0][2]);
            acc[0][3] = fmaf(a.x, b.w, acc[0][3]);
            acc[1][0] = fmaf(a.y, b.x, acc[1][0]);
            acc[1][1] = fmaf(a.y, b.y, acc[1][1]);
            acc[1][2] = fmaf(a.y, b.z, acc[1][2]);
            acc[1][3] = fmaf(a.y, b.w, acc[1][3]);
            acc[2][0] = fmaf(a.z, b.x, acc[2][0]);
            acc[2][1] = fmaf(a.z, b.y, acc[2][1]);
            acc[2][2] = fmaf(a.z, b.z, acc[2][2]);
            acc[2][3] = fmaf(a.z, b.w, acc[2][3]);
            acc[3][0] = fmaf(a.w, b.x, acc[3][0]);
            acc[3][1] = fmaf(a.w, b.y, acc[3][1]);
            acc[3][2] = fmaf(a.w, b.z, acc[3][2]);
            acc[3][3] = fmaf(a.w, b.w, acc[3][3]);
        }
        __syncthreads();
    }

    float4 bv = {0.f, 0.f, 0.f, 0.f};
    if (bias) bv = *reinterpret_cast<const float4*>(bias + colBase + tc);
#pragma unroll
    for (int i = 0; i < 4; ++i) {
        int row = rowBase + tr + i;
        if (row < M) {
            ushort4 o = { f2bf(acc[i][0] + bv.x), f2bf(acc[i][1] + bv.y),
                          f2bf(acc[i][2] + bv.z), f2bf(acc[i][3] + bv.w) };
            *reinterpret_cast<ushort4*>(C + (size_t)row * N + colBase + tc) = o;
        }
    }
}

// ---------------- counting sort by dst: hist / scan / scatter(perm) ---------
__global__ void hist_kernel(const int* __restrict__ dst, int* __restrict__ cnt, int E) {
    int i = blockIdx.x * 256 + threadIdx.x;
    if (i < E) atomicAdd(&cnt[dst[i]], 1);
}

__global__ __launch_bounds__(256) void scan1(const int* __restrict__ cnt,
                                             int* __restrict__ row_ptr,
                                             int* __restrict__ partials, int n) {
    __shared__ int sums[256];
    int tid = threadIdx.x;
    int base = blockIdx.x * 1024;
    int v[4]; int tsum = 0;
#pragma unroll
    for (int j = 0; j < 4; ++j) {
        int idx = base + tid * 4 + j;
        v[j] = (idx < n) ? cnt[idx] : 0;
        tsum += v[j];
    }
    sums[tid] = tsum;
    __syncthreads();
    for (int off = 1; off < 256; off <<= 1) {
        int x = (tid >= off) ? sums[tid - off] : 0;
        __syncthreads();
        sums[tid] += x;
        __syncthreads();
    }
    int run = sums[tid] - tsum;
#pragma unroll
    for (int j = 0; j < 4; ++j) {
        int idx = base + tid * 4 + j;
        if (idx < n) row_ptr[idx] = run;
        run += v[j];
    }
    if (tid == 255) partials[blockIdx.x] = sums[255];
}

__global__ __launch_bounds__(256) void scan2(int* __restrict__ partials, int nb) {
    __shared__ int s[256];
    int tid = threadIdx.x;
    int orig = (tid < nb) ? partials[tid] : 0;
    s[tid] = orig;
    __syncthreads();
    for (int off = 1; off < 256; off <<= 1) {
        int x = (tid >= off) ? s[tid - off] : 0;
        __syncthreads();
        s[tid] += x;
        __syncthreads();
    }
    if (tid < nb) partials[tid] = s[tid] - orig;
}

__global__ void scan3(int* __restrict__ row_ptr, const int* __restrict__ partials,
                      int n, int E) {
    int i = blockIdx.x * 256 + threadIdx.x;
    if (i < n) row_ptr[i] += partials[i >> 10];
    if (i == 0) row_ptr[n] = E;
}

__global__ void scatter_kernel(const int* __restrict__ dst,
                               const int* __restrict__ row_ptr, int* __restrict__ cursor,
                               int* __restrict__ perm, int E) {
    int i = blockIdx.x * 256 + threadIdx.x;
    if (i >= E) return;
    int d = dst[i];
    int pos = row_ptr[d] + atomicAdd(&cursor[d], 1);
    perm[pos] = i;
}

// ---------------- per-edge logits -> exp (ORIGINAL edge order) --------------
// 16 lanes per edge; lane l covers features 4l..4l+3 (head h = l/4).
// src/dst/reward reads and a_s writes are coalesced; f_ni/f_nj gathers inherent.
__global__ __launch_bounds__(256) void edge_logits(
    const unsigned short* __restrict__ f_ni, const unsigned short* __restrict__ f_nj,
    const int* __restrict__ src, const int* __restrict__ dst,
    const float* __restrict__ reward, const float* __restrict__ wsum,
    const float* __restrict__ b_e, const float* __restrict__ attn,
    float* __restrict__ a_s, int E)
{
    int gid = blockIdx.x * 256 + threadIdx.x;
    int q = gid >> 4;
    if (q >= E) return;
    int l = threadIdx.x & 15;
    int sn = src[q], dn = dst[q];
    float r = reward[q];
    ushort4 ui = *reinterpret_cast<const ushort4*>(f_ni + (size_t)sn * HE + 4 * l);
    ushort4 uj = *reinterpret_cast<const ushort4*>(f_nj + (size_t)dn * HE + 4 * l);
    float4 ws = *reinterpret_cast<const float4*>(wsum + 4 * l);
    float4 be = *reinterpret_cast<const float4*>(b_e + 4 * l);
    float4 at = *reinterpret_cast<const float4*>(attn + 4 * l);
    float t = 0.f, v;
    v = bf2f(ui.x) + bf2f(uj.x) + r * ws.x + be.x; v = (v >= 0.f) ? v : LEAKY * v; t += v * at.x;
    v = bf2f(ui.y) + bf2f(uj.y) + r * ws.y + be.y; v = (v >= 0.f) ? v : LEAKY * v; t += v * at.y;
    v = bf2f(ui.z) + bf2f(uj.z) + r * ws.z + be.z; v = (v >= 0.f) ? v : LEAKY * v; t += v * at.z;
    v = bf2f(ui.w) + bf2f(uj.w) + r * ws.w + be.w; v = (v >= 0.f) ? v : LEAKY * v; t += v * at.w;
    t += __shfl_xor(t, 1);
    t += __shfl_xor(t, 2);
    if ((l & 3) == 0) a_s[(size_t)q * NHEAD + (l >> 2)] = __expf(t);
}

// ---------------- aggregation: one wave per dst node ------------------------
// Phase A: lane-parallel (lane i -> slot beg+i) gathers of perm/src/a_s, staged
// to LDS; float4 denominator reduced across lanes. Phase B: weighted h_src
// gather with all indices/weights coming from LDS (independent loads, unroll).
__global__ __launch_bounds__(256) void aggregate(
    const unsigned short* __restrict__ h_src, const float* __restrict__ a_s,
    const int* __restrict__ src, const int* __restrict__ perm,
    const int* __restrict__ row_ptr, float* __restrict__ out, int Nd)
{
    __shared__ int   s_sn[4][64];
    __shared__ float s_w[4][64][4];
    int wv = threadIdx.x >> 6;
    int lane = threadIdx.x & 63;
    int d = blockIdx.x * 4 + wv;
    if (d >= Nd) return;
    int beg = row_ptr[d], end = row_ptr[d + 1];

    // Phase A: denominators (and stage first 64 slots)
    float4 den = {0.f, 0.f, 0.f, 0.f};
    for (int i = beg + lane; i < end; i += 64) {
        int eid = perm[i];
        float4 ev = *reinterpret_cast<const float4*>(a_s + (size_t)eid * NHEAD);
        if (i - beg < 64) {
            s_sn[wv][lane] = src[eid];
            *reinterpret_cast<float4*>(&s_w[wv][lane][0]) = ev;
        }
        den.x += ev.x; den.y += ev.y; den.z += ev.z; den.w += ev.w;
    }
#pragma unroll
    for (int off = 1; off < 64; off <<= 1) {
        den.x += __shfl_xor(den.x, off);
        den.y += __shfl_xor(den.y, off);
        den.z += __shfl_xor(den.z, off);
        den.w += __shfl_xor(den.w, off);
    }
    float4 inv = { den.x > 0.f ? 1.f / den.x : 0.f,
                   den.y > 0.f ? 1.f / den.y : 0.f,
                   den.z > 0.f ? 1.f / den.z : 0.f,
                   den.w > 0.f ? 1.f / den.w : 0.f };
    int h = lane >> 4;
    float invh = (h == 0) ? inv.x : (h == 1) ? inv.y : (h == 2) ? inv.z : inv.w;

    // Phase B: weighted aggregation, chunks of 64 slots
    float a0 = 0.f, a1 = 0.f, a2 = 0.f, a3 = 0.f;
    for (int chunk = beg; chunk < end; chunk += 64) {
        if (chunk != beg) {     // restage (rare: degree > 64)
            int i = chunk + lane;
            if (i < end) {
                int eid = perm[i];
                s_sn[wv][lane] = src[eid];
                *reinterpret_cast<float4*>(&s_w[wv][lane][0]) =
                    *reinterpret_cast<const float4*>(a_s + (size_t)eid * NHEAD);
            }
        }
        int n = min(64, end - chunk);
#pragma unroll 4
        for (int idx = 0; idx < n; ++idx) {
            int sn = s_sn[wv][idx];
            float w = s_w[wv][idx][h] * invh;
            ushort4 u = *reinterpret_cast<const ushort4*>(h_src + (size_t)sn * HN + lane * 4);
            a0 = fmaf(w, bf2f(u.x), a0);
            a1 = fmaf(w, bf2f(u.y), a1);
            a2 = fmaf(w, bf2f(u.z), a2);
            a3 = fmaf(w, bf2f(u.w), a3);
        }
    }
    a0 += __shfl_xor(a0, 16); a0 += __shfl_xor(a0, 32);
    a1 += __shfl_xor(a1, 16); a1 += __shfl_xor(a1, 32);
    a2 += __shfl_xor(a2, 16); a2 += __shfl_xor(a2, 32);
    a3 += __shfl_xor(a3, 16); a3 += __shfl_xor(a3, 32);
    if (lane < 16) {
        float4 o = { fmaxf(a0 * 0.25f, 0.f), fmaxf(a1 * 0.25f, 0.f),
                     fmaxf(a2 * 0.25f, 0.f), fmaxf(a3 * 0.25f, 0.f) };
        *reinterpret_cast<float4*>(out + (size_t)d * OUT_NODE + lane * 4) = o;
    }
}

static inline char* align256(char* p) {
    return (char*)(((uintptr_t)p + 255) & ~(uintptr_t)255);
}

extern "C" void kernel_launch(void* const* d_in, const int* in_sizes, int n_in,
                              void* d_out, int out_size, void* d_ws, size_t ws_size,
                              hipStream_t stream) {
    const float* nfeats    = (const float*)d_in[0];
    const float* dst_feats = (const float*)d_in[1];
    const float* reward    = (const float*)d_in[2];
    const int*   src       = (const int*)d_in[3];
    const int*   dst       = (const int*)d_in[4];
    const float* W_ns      = (const float*)d_in[5];
    const float* b_ns      = (const float*)d_in[6];
    const float* W_ni      = (const float*)d_in[7];
    const float* W_nj      = (const float*)d_in[8];
    const float* W_fij     = (const float*)d_in[9];
    const float* attn      = (const float*)d_in[10];
    const float* b_e       = (const float*)d_in[11];
    float* out = (float*)d_out;

    const int Ns = in_sizes[0] / IN_NODE;
    const int Nd = in_sizes[1] / IN_NODE;
    const int E  = in_sizes[2];

    char* ws = (char*)d_ws;
    unsigned short* f_ni  = (unsigned short*)ws; ws = align256(ws + (size_t)Ns * HE * 2);
    unsigned short* f_nj  = (unsigned short*)ws; ws = align256(ws + (size_t)Nd * HE * 2);
    unsigned short* h_src = (unsigned short*)ws; ws = align256(ws + (size_t)Ns * HN * 2);
    float* wsum    = (float*)ws; ws = align256(ws + HE * 4);
    int*   cnt     = (int*)ws;   ws = align256(ws + (size_t)Nd * 4);
    int*   row_ptr = (int*)ws;   ws = align256(ws + (size_t)(Nd + 1) * 4);
    int*   cursor  = (int*)ws;   ws = align256(ws + (size_t)Nd * 4);
    int*   partials= (int*)ws;   ws = align256(ws + 256 * 4);
    int*   perm    = (int*)ws;   ws = align256(ws + (size_t)E * 4);
    float* a_s     = (float*)ws; ws = align256(ws + (size_t)E * NHEAD * 4);

    hipMemsetAsync(cnt, 0, (size_t)Nd * 4, stream);
    hipMemsetAsync(cursor, 0, (size_t)Nd * 4, stream);

    prep_wsum<<<1, 64, 0, stream>>>(W_fij, wsum);

    dim3 blk(256);
    gemm_k128<<<dim3((Ns + 63) / 64, 1), blk, 0, stream>>>(nfeats,    W_ni, nullptr, f_ni, Ns, HE);
    gemm_k128<<<dim3((Nd + 63) / 64, 1), blk, 0, stream>>>(dst_feats, W_nj, nullptr, f_nj, Nd, HE);
    gemm_k128<<<dim3((Ns + 63) / 64, 4), blk, 0, stream>>>(nfeats,    W_ns, b_ns,    h_src, Ns, HN);

    hist_kernel<<<(E + 255) / 256, 256, 0, stream>>>(dst, cnt, E);
    int nb = (Nd + 1023) / 1024;
    scan1<<<nb, 256, 0, stream>>>(cnt, row_ptr, partials, Nd);
    scan2<<<1, 256, 0, stream>>>(partials, nb);
    scan3<<<(Nd + 255) / 256, 256, 0, stream>>>(row_ptr, partials, Nd, E);
    scatter_kernel<<<(E + 255) / 256, 256, 0, stream>>>(dst, row_ptr, cursor, perm, E);

    edge_logits<<<(int)(((size_t)E * 16 + 255) / 256), 256, 0, stream>>>(
        f_ni, f_nj, src, dst, reward, wsum, b_e, attn, a_s, E);

    aggregate<<<(Nd + 3) / 4, 256, 0, stream>>>(h_src, a_s, src, perm, row_ptr, out, Nd);
}

// Round 5
// 359.662 us; speedup vs baseline: 1.3497x; 1.1214x over previous
//
#include <hip/hip_runtime.h>

#define IN_NODE 128
#define OUT_NODE 64
#define OUT_EDGE 16
#define NHEAD 4
#define HN (NHEAD * OUT_NODE)  // 256
#define HE (NHEAD * OUT_EDGE)  // 64
#define LEAKY 0.01f

__device__ __forceinline__ float bf2f(unsigned short u) {
    union { unsigned u; float f; } v; v.u = ((unsigned)u) << 16; return v.f;
}
__device__ __forceinline__ unsigned short f2bf(float x) {
    union { float f; unsigned u; } v; v.f = x;
    unsigned r = v.u + 0x7FFF + ((v.u >> 16) & 1);   // RNE
    return (unsigned short)(r >> 16);
}
__device__ __forceinline__ float h2f(unsigned short u) {
    union { unsigned short u; _Float16 f; } v; v.u = u; return (float)v.f;
}
__device__ __forceinline__ unsigned short f2h(float x) {
    union { unsigned short u; _Float16 f; } v; v.f = (_Float16)x; return v.u;
}

// ---------------- wsum[k] = sum_c W_fij[c][k]  (16x64 -> 64) ----------------
__global__ void prep_wsum(const float* __restrict__ W_fij, float* __restrict__ wsum) {
    int k = threadIdx.x;
    float s = 0.f;
#pragma unroll
    for (int c = 0; c < 16; ++c) s += W_fij[c * 64 + k];
    wsum[k] = s;
}

// ------- fused GEMMs: y==0 -> f_ni, y in 1..4 -> h_src slice, y==5 -> f_nj --
__global__ __launch_bounds__(256) void gemm_all(
    const float* __restrict__ nfeats, const float* __restrict__ dst_feats,
    const float* __restrict__ W_ni, const float* __restrict__ W_ns,
    const float* __restrict__ W_nj, const float* __restrict__ b_ns,
    unsigned short* __restrict__ f_ni, unsigned short* __restrict__ h_src,
    unsigned short* __restrict__ f_nj, int Ns, int Nd)
{
    const int by = blockIdx.y;
    const float* A; const float* W; const float* bias;
    unsigned short* C; int N, colBase, M;
    if (by == 0)      { A = nfeats;    W = W_ni; bias = nullptr; C = f_ni;  N = 64;  colBase = 0;             M = Ns; }
    else if (by <= 4) { A = nfeats;    W = W_ns; bias = b_ns;    C = h_src; N = 256; colBase = (by - 1) * 64; M = Ns; }
    else              { A = dst_feats; W = W_nj; bias = nullptr; C = f_nj;  N = 64;  colBase = 0;             M = Nd; }

    __shared__ float At[64 * 68];   // [k][row]
    __shared__ float Ws[64 * 64];   // [k][col]
    const int t = threadIdx.x;
    const int rowBase = blockIdx.x * 64;
    if (rowBase >= M) return;
    const int tr = (t >> 4) << 2;
    const int tc = (t & 15) << 2;
    float acc[4][4] = {};

    for (int kt = 0; kt < 128; kt += 64) {
#pragma unroll
        for (int i = 0; i < 4; ++i) {           // stage A transposed
            int f4 = t + i * 256;
            int r = f4 >> 4;
            int kf = (f4 & 15) << 2;
            float4 v = {0.f, 0.f, 0.f, 0.f};
            int row = rowBase + r;
            if (row < M) v = *reinterpret_cast<const float4*>(A + (size_t)row * 128 + kt + kf);
            At[(kf + 0) * 68 + r] = v.x;
            At[(kf + 1) * 68 + r] = v.y;
            At[(kf + 2) * 68 + r] = v.z;
            At[(kf + 3) * 68 + r] = v.w;
        }
#pragma unroll
        for (int i = 0; i < 4; ++i) {           // stage W
            int f4 = t + i * 256;
            int k = f4 >> 4;
            int cf = (f4 & 15) << 2;
            float4 v = *reinterpret_cast<const float4*>(W + (size_t)(kt + k) * N + colBase + cf);
            *reinterpret_cast<float4*>(Ws + k * 64 + cf) = v;
        }
        __syncthreads();
#pragma unroll 8
        for (int k = 0; k < 64; ++k) {
            float4 b = *reinterpret_cast<const float4*>(Ws + k * 64 + tc);
            float4 a = *reinterpret_cast<const float4*>(At + k * 68 + tr);
            acc[0][0] = fmaf(a.x, b.x, acc[0][0]);
            acc[0][1] = fmaf(a.x, b.y, acc[0][1]);
            acc[0][2] = fmaf(a.x, b.z, acc[0][2]);
            acc[0][3] = fmaf(a.x, b.w, acc[0][3]);
            acc[1][0] = fmaf(a.y, b.x, acc[1][0]);
            acc[1][1] = fmaf(a.y, b.y, acc[1][1]);
            acc[1][2] = fmaf(a.y, b.z, acc[1][2]);
            acc[1][3] = fmaf(a.y, b.w, acc[1][3]);
            acc[2][0] = fmaf(a.z, b.x, acc[2][0]);
            acc[2][1] = fmaf(a.z, b.y, acc[2][1]);
            acc[2][2] = fmaf(a.z, b.z, acc[2][2]);
            acc[2][3] = fmaf(a.z, b.w, acc[2][3]);
            acc[3][0] = fmaf(a.w, b.x, acc[3][0]);
            acc[3][1] = fmaf(a.w, b.y, acc[3][1]);
            acc[3][2] = fmaf(a.w, b.z, acc[3][2]);
            acc[3][3] = fmaf(a.w, b.w, acc[3][3]);
        }
        __syncthreads();
    }

    float4 bv = {0.f, 0.f, 0.f, 0.f};
    if (bias) bv = *reinterpret_cast<const float4*>(bias + colBase + tc);
#pragma unroll
    for (int i = 0; i < 4; ++i) {
        int row = rowBase + tr + i;
        if (row < M) {
            ushort4 o = { f2bf(acc[i][0] + bv.x), f2bf(acc[i][1] + bv.y),
                          f2bf(acc[i][2] + bv.z), f2bf(acc[i][3] + bv.w) };
            *reinterpret_cast<ushort4*>(C + (size_t)row * N + colBase + tc) = o;
        }
    }
}

// ---------------- scans for counting sort -----------------------------------
__global__ __launch_bounds__(256) void scan1(const int* __restrict__ cnt,
                                             int* __restrict__ row_ptr,
                                             int* __restrict__ partials, int n) {
    __shared__ int sums[256];
    int tid = threadIdx.x;
    int base = blockIdx.x * 1024;
    int v[4]; int tsum = 0;
#pragma unroll
    for (int j = 0; j < 4; ++j) {
        int idx = base + tid * 4 + j;
        v[j] = (idx < n) ? cnt[idx] : 0;
        tsum += v[j];
    }
    sums[tid] = tsum;
    __syncthreads();
    for (int off = 1; off < 256; off <<= 1) {
        int x = (tid >= off) ? sums[tid - off] : 0;
        __syncthreads();
        sums[tid] += x;
        __syncthreads();
    }
    int run = sums[tid] - tsum;
#pragma unroll
    for (int j = 0; j < 4; ++j) {
        int idx = base + tid * 4 + j;
        if (idx < n) row_ptr[idx] = run;
        run += v[j];
    }
    if (tid == 255) partials[blockIdx.x] = sums[255];
}

__global__ __launch_bounds__(256) void scan2(int* __restrict__ partials, int nb) {
    __shared__ int s[256];
    int tid = threadIdx.x;
    int orig = (tid < nb) ? partials[tid] : 0;
    s[tid] = orig;
    __syncthreads();
    for (int off = 1; off < 256; off <<= 1) {
        int x = (tid >= off) ? s[tid - off] : 0;
        __syncthreads();
        s[tid] += x;
        __syncthreads();
    }
    if (tid < nb) partials[tid] = s[tid] - orig;
}

__global__ void scan3(int* __restrict__ row_ptr, const int* __restrict__ partials,
                      int n, int E) {
    int i = blockIdx.x * 256 + threadIdx.x;
    if (i < n) row_ptr[i] += partials[i >> 10];
    if (i == 0) row_ptr[n] = E;
}

__global__ void scatter_kernel(const int* __restrict__ dst,
                               const int* __restrict__ row_ptr, int* __restrict__ cursor,
                               int* __restrict__ perm, int E) {
    int i = blockIdx.x * 256 + threadIdx.x;
    if (i >= E) return;
    int d = dst[i];
    int pos = row_ptr[d] + atomicAdd(&cursor[d], 1);
    perm[pos] = i;
}

// ------- per-edge logits -> exp (f16 packed with src) + dst histogram -------
// 16 lanes per edge; lane l covers features 4l..4l+3 (head h = l/4).
// pk[e] = { half2(e0,e1), half2(e2,e3), src, 0 }
__global__ __launch_bounds__(256) void edge_logits(
    const unsigned short* __restrict__ f_ni, const unsigned short* __restrict__ f_nj,
    const int* __restrict__ src, const int* __restrict__ dst,
    const float* __restrict__ reward, const float* __restrict__ wsum,
    const float* __restrict__ b_e, const float* __restrict__ attn,
    uint4* __restrict__ pk, int* __restrict__ cnt, int E)
{
    int gid = blockIdx.x * 256 + threadIdx.x;
    int q = gid >> 4;
    if (q >= E) return;
    int lane = threadIdx.x & 63;
    int l = lane & 15;
    int sn = src[q], dn = dst[q];
    float r = reward[q];
    ushort4 ui = *reinterpret_cast<const ushort4*>(f_ni + (size_t)sn * HE + 4 * l);
    ushort4 uj = *reinterpret_cast<const ushort4*>(f_nj + (size_t)dn * HE + 4 * l);
    float4 ws = *reinterpret_cast<const float4*>(wsum + 4 * l);
    float4 be = *reinterpret_cast<const float4*>(b_e + 4 * l);
    float4 at = *reinterpret_cast<const float4*>(attn + 4 * l);
    float t = 0.f, v;
    v = bf2f(ui.x) + bf2f(uj.x) + r * ws.x + be.x; v = (v >= 0.f) ? v : LEAKY * v; t += v * at.x;
    v = bf2f(ui.y) + bf2f(uj.y) + r * ws.y + be.y; v = (v >= 0.f) ? v : LEAKY * v; t += v * at.y;
    v = bf2f(ui.z) + bf2f(uj.z) + r * ws.z + be.z; v = (v >= 0.f) ? v : LEAKY * v; t += v * at.z;
    v = bf2f(ui.w) + bf2f(uj.w) + r * ws.w + be.w; v = (v >= 0.f) ? v : LEAKY * v; t += v * at.w;
    t += __shfl_xor(t, 1);
    t += __shfl_xor(t, 2);           // lanes 4h..4h+3 hold head h's logit
    float ev = __expf(t);
    int g16 = lane & ~15;
    float e0 = __shfl(ev, g16 + 0);
    float e1 = __shfl(ev, g16 + 4);
    float e2 = __shfl(ev, g16 + 8);
    float e3 = __shfl(ev, g16 + 12);
    if (l == 0) {
        uint4 p;
        p.x = (unsigned)f2h(e0) | ((unsigned)f2h(e1) << 16);
        p.y = (unsigned)f2h(e2) | ((unsigned)f2h(e3) << 16);
        p.z = (unsigned)sn;
        p.w = 0u;
        pk[q] = p;
        atomicAdd(&cnt[dn], 1);
    }
}

// ---------------- aggregation: one wave per dst node ------------------------
__global__ __launch_bounds__(256) void aggregate(
    const unsigned short* __restrict__ h_src, const uint4* __restrict__ pk,
    const int* __restrict__ perm, const int* __restrict__ row_ptr,
    float* __restrict__ out, int Nd)
{
    __shared__ int   s_sn[4][64];
    __shared__ float s_w[4][64][4];
    int wv = threadIdx.x >> 6;
    int lane = threadIdx.x & 63;
    int d = blockIdx.x * 4 + wv;
    if (d >= Nd) return;
    int beg = row_ptr[d], end = row_ptr[d + 1];

    // Phase A: stage first 64 slots (sentinel -1 past end) + denominators
    float4 den = {0.f, 0.f, 0.f, 0.f};
    {
        int i = beg + lane;
        if (i < end) {
            uint4 p = pk[perm[i]];
            float e0 = h2f((unsigned short)(p.x & 0xffff));
            float e1 = h2f((unsigned short)(p.x >> 16));
            float e2 = h2f((unsigned short)(p.y & 0xffff));
            float e3 = h2f((unsigned short)(p.y >> 16));
            s_sn[wv][lane] = (int)p.z;
            float4 w4 = {e0, e1, e2, e3};
            *reinterpret_cast<float4*>(&s_w[wv][lane][0]) = w4;
            den.x += e0; den.y += e1; den.z += e2; den.w += e3;
        } else {
            s_sn[wv][lane] = -1;
        }
        for (i += 64; i < end; i += 64) {     // degree > 64 tail
            uint4 p = pk[perm[i]];
            den.x += h2f((unsigned short)(p.x & 0xffff));
            den.y += h2f((unsigned short)(p.x >> 16));
            den.z += h2f((unsigned short)(p.y & 0xffff));
            den.w += h2f((unsigned short)(p.y >> 16));
        }
    }
#pragma unroll
    for (int off = 1; off < 64; off <<= 1) {
        den.x += __shfl_xor(den.x, off);
        den.y += __shfl_xor(den.y, off);
        den.z += __shfl_xor(den.z, off);
        den.w += __shfl_xor(den.w, off);
    }
    int h = lane >> 4;
    float dh = (h == 0) ? den.x : (h == 1) ? den.y : (h == 2) ? den.z : den.w;
    float invh = (dh > 0.f) ? 1.f / dh : 0.f;

    // Phase B: weighted aggregation, 8-deep MLP, sentinel-padded
    float a0 = 0.f, a1 = 0.f, a2 = 0.f, a3 = 0.f;
    for (int chunk = beg; chunk < end; chunk += 64) {
        if (chunk != beg) {     // restage (rare: degree > 64)
            int i = chunk + lane;
            if (i < end) {
                uint4 p = pk[perm[i]];
                float4 w4 = { h2f((unsigned short)(p.x & 0xffff)),
                              h2f((unsigned short)(p.x >> 16)),
                              h2f((unsigned short)(p.y & 0xffff)),
                              h2f((unsigned short)(p.y >> 16)) };
                s_sn[wv][lane] = (int)p.z;
                *reinterpret_cast<float4*>(&s_w[wv][lane][0]) = w4;
            } else {
                s_sn[wv][lane] = -1;
            }
        }
        int n = min(64, end - chunk);
        int npad = (n + 7) & ~7;
        for (int base = 0; base < npad; base += 8) {
#pragma unroll
            for (int j = 0; j < 8; ++j) {
                int idx = base + j;
                int sn = s_sn[wv][idx];
                float w = (sn >= 0) ? s_w[wv][idx][h] * invh : 0.f;
                int sa = (sn >= 0) ? sn : 0;
                ushort4 u = *reinterpret_cast<const ushort4*>(h_src + (size_t)sa * HN + lane * 4);
                a0 = fmaf(w, bf2f(u.x), a0);
                a1 = fmaf(w, bf2f(u.y), a1);
                a2 = fmaf(w, bf2f(u.z), a2);
                a3 = fmaf(w, bf2f(u.w), a3);
            }
        }
    }
    a0 += __shfl_xor(a0, 16); a0 += __shfl_xor(a0, 32);
    a1 += __shfl_xor(a1, 16); a1 += __shfl_xor(a1, 32);
    a2 += __shfl_xor(a2, 16); a2 += __shfl_xor(a2, 32);
    a3 += __shfl_xor(a3, 16); a3 += __shfl_xor(a3, 32);
    if (lane < 16) {
        float4 o = { fmaxf(a0 * 0.25f, 0.f), fmaxf(a1 * 0.25f, 0.f),
                     fmaxf(a2 * 0.25f, 0.f), fmaxf(a3 * 0.25f, 0.f) };
        *reinterpret_cast<float4*>(out + (size_t)d * OUT_NODE + lane * 4) = o;
    }
}

static inline char* align256(char* p) {
    return (char*)(((uintptr_t)p + 255) & ~(uintptr_t)255);
}

extern "C" void kernel_launch(void* const* d_in, const int* in_sizes, int n_in,
                              void* d_out, int out_size, void* d_ws, size_t ws_size,
                              hipStream_t stream) {
    const float* nfeats    = (const float*)d_in[0];
    const float* dst_feats = (const float*)d_in[1];
    const float* reward    = (const float*)d_in[2];
    const int*   src       = (const int*)d_in[3];
    const int*   dst       = (const int*)d_in[4];
    const float* W_ns      = (const float*)d_in[5];
    const float* b_ns      = (const float*)d_in[6];
    const float* W_ni      = (const float*)d_in[7];
    const float* W_nj      = (const float*)d_in[8];
    const float* W_fij     = (const float*)d_in[9];
    const float* attn      = (const float*)d_in[10];
    const float* b_e       = (const float*)d_in[11];
    float* out = (float*)d_out;

    const int Ns = in_sizes[0] / IN_NODE;
    const int Nd = in_sizes[1] / IN_NODE;
    const int E  = in_sizes[2];

    char* ws = (char*)d_ws;
    unsigned short* f_ni  = (unsigned short*)ws; ws = align256(ws + (size_t)Ns * HE * 2);
    unsigned short* f_nj  = (unsigned short*)ws; ws = align256(ws + (size_t)Nd * HE * 2);
    unsigned short* h_src = (unsigned short*)ws; ws = align256(ws + (size_t)Ns * HN * 2);
    float* wsum    = (float*)ws; ws = align256(ws + HE * 4);
    int*   cnt     = (int*)ws;   ws = align256(ws + (size_t)Nd * 4);
    int*   row_ptr = (int*)ws;   ws = align256(ws + (size_t)(Nd + 1) * 4);
    int*   cursor  = (int*)ws;   ws = align256(ws + (size_t)Nd * 4);
    int*   partials= (int*)ws;   ws = align256(ws + 256 * 4);
    int*   perm    = (int*)ws;   ws = align256(ws + (size_t)E * 4);
    uint4* pk      = (uint4*)ws; ws = align256(ws + (size_t)E * 16);

    hipMemsetAsync(cnt, 0, (size_t)Nd * 4, stream);
    hipMemsetAsync(cursor, 0, (size_t)Nd * 4, stream);

    prep_wsum<<<1, 64, 0, stream>>>(W_fij, wsum);

    gemm_all<<<dim3((Ns + 63) / 64, 6), 256, 0, stream>>>(
        nfeats, dst_feats, W_ni, W_ns, W_nj, b_ns, f_ni, h_src, f_nj, Ns, Nd);

    edge_logits<<<(int)(((size_t)E * 16 + 255) / 256), 256, 0, stream>>>(
        f_ni, f_nj, src, dst, reward, wsum, b_e, attn, pk, cnt, E);

    int nb = (Nd + 1023) / 1024;
    scan1<<<nb, 256, 0, stream>>>(cnt, row_ptr, partials, Nd);
    scan2<<<1, 256, 0, stream>>>(partials, nb);
    scan3<<<(Nd + 255) / 256, 256, 0, stream>>>(row_ptr, partials, Nd, E);
    scatter_kernel<<<(E + 255) / 256, 256, 0, stream>>>(dst, row_ptr, cursor, perm, E);

    aggregate<<<(Nd + 3) / 4, 256, 0, stream>>>(h_src, pk, perm, row_ptr, out, Nd);
}

// Round 6
// 346.303 us; speedup vs baseline: 1.4018x; 1.0386x over previous
//
#include <hip/hip_runtime.h>

#define IN_NODE 128
#define OUT_NODE 64
#define OUT_EDGE 16
#define NHEAD 4
#define HN (NHEAD * OUT_NODE)  // 256
#define HE (NHEAD * OUT_EDGE)  // 64
#define LEAKY 0.01f

__device__ __forceinline__ float bf2f(unsigned short u) {
    union { unsigned u; float f; } v; v.u = ((unsigned)u) << 16; return v.f;
}
__device__ __forceinline__ unsigned short f2bf(float x) {
    union { float f; unsigned u; } v; v.f = x;
    unsigned r = v.u + 0x7FFF + ((v.u >> 16) & 1);   // RNE
    return (unsigned short)(r >> 16);
}
__device__ __forceinline__ float h2f(unsigned short u) {
    union { unsigned short u; _Float16 f; } v; v.u = u; return (float)v.f;
}
__device__ __forceinline__ unsigned short f2h(float x) {
    union { unsigned short u; _Float16 f; } v; v.f = (_Float16)x; return v.u;
}

// ---------------- wsum[k] = sum_c W_fij[c][k]  (16x64 -> 64) ----------------
__global__ void prep_wsum(const float* __restrict__ W_fij, float* __restrict__ wsum) {
    int k = threadIdx.x;
    float s = 0.f;
#pragma unroll
    for (int c = 0; c < 16; ++c) s += W_fij[c * 64 + k];
    wsum[k] = s;
}

// ------- fused GEMMs: y==0 -> f_ni, y in 1..4 -> h_src slice, y==5 -> f_nj --
// A staged ROW-MAJOR (float4 stores, 2-way max = free); a-fragment reads are
// broadcast across 16 lanes (free). Ws float4 both ways (2-way max).
__global__ __launch_bounds__(256) void gemm_all(
    const float* __restrict__ nfeats, const float* __restrict__ dst_feats,
    const float* __restrict__ W_ni, const float* __restrict__ W_ns,
    const float* __restrict__ W_nj, const float* __restrict__ b_ns,
    unsigned short* __restrict__ f_ni, unsigned short* __restrict__ h_src,
    unsigned short* __restrict__ f_nj, int Ns, int Nd)
{
    const int by = blockIdx.y;
    const float* A; const float* W; const float* bias;
    unsigned short* C; int N, colBase, M;
    if (by == 0)      { A = nfeats;    W = W_ni; bias = nullptr; C = f_ni;  N = 64;  colBase = 0;             M = Ns; }
    else if (by <= 4) { A = nfeats;    W = W_ns; bias = b_ns;    C = h_src; N = 256; colBase = (by - 1) * 64; M = Ns; }
    else              { A = dst_feats; W = W_nj; bias = nullptr; C = f_nj;  N = 64;  colBase = 0;             M = Nd; }

    __shared__ float As[64 * 68];   // [row][k], +4 pad
    __shared__ float Ws[64 * 64];   // [k][col]
    const int t = threadIdx.x;
    const int rowBase = blockIdx.x * 64;
    if (rowBase >= M) return;
    const int tr = (t >> 4) << 2;
    const int tc = (t & 15) << 2;
    float acc[4][4] = {};

    for (int kt = 0; kt < 128; kt += 64) {
#pragma unroll
        for (int i = 0; i < 4; ++i) {           // stage A row-major, float4
            int f4 = t + i * 256;
            int r = f4 >> 4;
            int kf = (f4 & 15) << 2;
            float4 v = {0.f, 0.f, 0.f, 0.f};
            int row = rowBase + r;
            if (row < M) v = *reinterpret_cast<const float4*>(A + (size_t)row * 128 + kt + kf);
            *reinterpret_cast<float4*>(As + r * 68 + kf) = v;
        }
#pragma unroll
        for (int i = 0; i < 4; ++i) {           // stage W
            int f4 = t + i * 256;
            int k = f4 >> 4;
            int cf = (f4 & 15) << 2;
            float4 v = *reinterpret_cast<const float4*>(W + (size_t)(kt + k) * N + colBase + cf);
            *reinterpret_cast<float4*>(Ws + k * 64 + cf) = v;
        }
        __syncthreads();
#pragma unroll 8
        for (int k = 0; k < 64; ++k) {
            float4 b = *reinterpret_cast<const float4*>(Ws + k * 64 + tc);
            float a0 = As[(tr + 0) * 68 + k];
            float a1 = As[(tr + 1) * 68 + k];
            float a2 = As[(tr + 2) * 68 + k];
            float a3 = As[(tr + 3) * 68 + k];
            acc[0][0] = fmaf(a0, b.x, acc[0][0]);
            acc[0][1] = fmaf(a0, b.y, acc[0][1]);
            acc[0][2] = fmaf(a0, b.z, acc[0][2]);
            acc[0][3] = fmaf(a0, b.w, acc[0][3]);
            acc[1][0] = fmaf(a1, b.x, acc[1][0]);
            acc[1][1] = fmaf(a1, b.y, acc[1][1]);
            acc[1][2] = fmaf(a1, b.z, acc[1][2]);
            acc[1][3] = fmaf(a1, b.w, acc[1][3]);
            acc[2][0] = fmaf(a2, b.x, acc[2][0]);
            acc[2][1] = fmaf(a2, b.y, acc[2][1]);
            acc[2][2] = fmaf(a2, b.z, acc[2][2]);
            acc[2][3] = fmaf(a2, b.w, acc[2][3]);
            acc[3][0] = fmaf(a3, b.x, acc[3][0]);
            acc[3][1] = fmaf(a3, b.y, acc[3][1]);
            acc[3][2] = fmaf(a3, b.z, acc[3][2]);
            acc[3][3] = fmaf(a3, b.w, acc[3][3]);
        }
        __syncthreads();
    }

    float4 bv = {0.f, 0.f, 0.f, 0.f};
    if (bias) bv = *reinterpret_cast<const float4*>(bias + colBase + tc);
#pragma unroll
    for (int i = 0; i < 4; ++i) {
        int row = rowBase + tr + i;
        if (row < M) {
            ushort4 o = { f2bf(acc[i][0] + bv.x), f2bf(acc[i][1] + bv.y),
                          f2bf(acc[i][2] + bv.z), f2bf(acc[i][3] + bv.w) };
            *reinterpret_cast<ushort4*>(C + (size_t)row * N + colBase + tc) = o;
        }
    }
}

// ---------------- scans for counting sort -----------------------------------
__global__ __launch_bounds__(256) void scan1(const int* __restrict__ cnt,
                                             int* __restrict__ row_ptr,
                                             int* __restrict__ partials, int n) {
    __shared__ int sums[256];
    int tid = threadIdx.x;
    int base = blockIdx.x * 1024;
    int v[4]; int tsum = 0;
#pragma unroll
    for (int j = 0; j < 4; ++j) {
        int idx = base + tid * 4 + j;
        v[j] = (idx < n) ? cnt[idx] : 0;
        tsum += v[j];
    }
    sums[tid] = tsum;
    __syncthreads();
    for (int off = 1; off < 256; off <<= 1) {
        int x = (tid >= off) ? sums[tid - off] : 0;
        __syncthreads();
        sums[tid] += x;
        __syncthreads();
    }
    int run = sums[tid] - tsum;
#pragma unroll
    for (int j = 0; j < 4; ++j) {
        int idx = base + tid * 4 + j;
        if (idx < n) row_ptr[idx] = run;
        run += v[j];
    }
    if (tid == 255) partials[blockIdx.x] = sums[255];
}

__global__ __launch_bounds__(256) void scan2(int* __restrict__ partials, int nb) {
    __shared__ int s[256];
    int tid = threadIdx.x;
    int orig = (tid < nb) ? partials[tid] : 0;
    s[tid] = orig;
    __syncthreads();
    for (int off = 1; off < 256; off <<= 1) {
        int x = (tid >= off) ? s[tid - off] : 0;
        __syncthreads();
        s[tid] += x;
        __syncthreads();
    }
    if (tid < nb) partials[tid] = s[tid] - orig;
}

__global__ void scan3(int* __restrict__ row_ptr, const int* __restrict__ partials,
                      int n, int E) {
    int i = blockIdx.x * 256 + threadIdx.x;
    if (i < n) row_ptr[i] += partials[i >> 10];
    if (i == 0) row_ptr[n] = E;
}

__global__ void scatter_kernel(const int* __restrict__ dst,
                               const int* __restrict__ row_ptr, int* __restrict__ cursor,
                               int* __restrict__ perm, int E) {
    int i = blockIdx.x * 256 + threadIdx.x;
    if (i >= E) return;
    int d = dst[i];
    int pos = row_ptr[d] + atomicAdd(&cursor[d], 1);
    perm[pos] = i;
}

// ------- per-edge logits -> exp (f16 packed with src) + dst histogram -------
__global__ __launch_bounds__(256) void edge_logits(
    const unsigned short* __restrict__ f_ni, const unsigned short* __restrict__ f_nj,
    const int* __restrict__ src, const int* __restrict__ dst,
    const float* __restrict__ reward, const float* __restrict__ wsum,
    const float* __restrict__ b_e, const float* __restrict__ attn,
    uint4* __restrict__ pk, int* __restrict__ cnt, int E)
{
    int gid = blockIdx.x * 256 + threadIdx.x;
    int q = gid >> 4;
    if (q >= E) return;
    int lane = threadIdx.x & 63;
    int l = lane & 15;
    int sn = src[q], dn = dst[q];
    float r = reward[q];
    ushort4 ui = *reinterpret_cast<const ushort4*>(f_ni + (size_t)sn * HE + 4 * l);
    ushort4 uj = *reinterpret_cast<const ushort4*>(f_nj + (size_t)dn * HE + 4 * l);
    float4 ws = *reinterpret_cast<const float4*>(wsum + 4 * l);
    float4 be = *reinterpret_cast<const float4*>(b_e + 4 * l);
    float4 at = *reinterpret_cast<const float4*>(attn + 4 * l);
    float t = 0.f, v;
    v = bf2f(ui.x) + bf2f(uj.x) + r * ws.x + be.x; v = (v >= 0.f) ? v : LEAKY * v; t += v * at.x;
    v = bf2f(ui.y) + bf2f(uj.y) + r * ws.y + be.y; v = (v >= 0.f) ? v : LEAKY * v; t += v * at.y;
    v = bf2f(ui.z) + bf2f(uj.z) + r * ws.z + be.z; v = (v >= 0.f) ? v : LEAKY * v; t += v * at.z;
    v = bf2f(ui.w) + bf2f(uj.w) + r * ws.w + be.w; v = (v >= 0.f) ? v : LEAKY * v; t += v * at.w;
    t += __shfl_xor(t, 1);
    t += __shfl_xor(t, 2);           // lanes 4h..4h+3 hold head h's logit
    float ev = __expf(t);
    int g16 = lane & ~15;
    float e0 = __shfl(ev, g16 + 0);
    float e1 = __shfl(ev, g16 + 4);
    float e2 = __shfl(ev, g16 + 8);
    float e3 = __shfl(ev, g16 + 12);
    if (l == 0) {
        uint4 p;
        p.x = (unsigned)f2h(e0) | ((unsigned)f2h(e1) << 16);
        p.y = (unsigned)f2h(e2) | ((unsigned)f2h(e3) << 16);
        p.z = (unsigned)sn;
        p.w = 0u;
        pk[q] = p;
        atomicAdd(&cnt[dn], 1);
    }
}

// ---------------- aggregation: one wave per dst node ------------------------
__global__ __launch_bounds__(256) void aggregate(
    const unsigned short* __restrict__ h_src, const uint4* __restrict__ pk,
    const int* __restrict__ perm, const int* __restrict__ row_ptr,
    float* __restrict__ out, int Nd)
{
    __shared__ int   s_sn[4][64];
    __shared__ float s_w[4][64][4];
    int wv = threadIdx.x >> 6;
    int lane = threadIdx.x & 63;
    int d = blockIdx.x * 4 + wv;
    if (d >= Nd) return;
    int beg = row_ptr[d], end = row_ptr[d + 1];

    // Phase A: stage first 64 slots (sentinel -1 past end) + denominators
    float4 den = {0.f, 0.f, 0.f, 0.f};
    {
        int i = beg + lane;
        if (i < end) {
            uint4 p = pk[perm[i]];
            float e0 = h2f((unsigned short)(p.x & 0xffff));
            float e1 = h2f((unsigned short)(p.x >> 16));
            float e2 = h2f((unsigned short)(p.y & 0xffff));
            float e3 = h2f((unsigned short)(p.y >> 16));
            s_sn[wv][lane] = (int)p.z;
            float4 w4 = {e0, e1, e2, e3};
            *reinterpret_cast<float4*>(&s_w[wv][lane][0]) = w4;
            den.x += e0; den.y += e1; den.z += e2; den.w += e3;
        } else {
            s_sn[wv][lane] = -1;
        }
        for (i += 64; i < end; i += 64) {     // degree > 64 tail
            uint4 p = pk[perm[i]];
            den.x += h2f((unsigned short)(p.x & 0xffff));
            den.y += h2f((unsigned short)(p.x >> 16));
            den.z += h2f((unsigned short)(p.y & 0xffff));
            den.w += h2f((unsigned short)(p.y >> 16));
        }
    }
#pragma unroll
    for (int off = 1; off < 64; off <<= 1) {
        den.x += __shfl_xor(den.x, off);
        den.y += __shfl_xor(den.y, off);
        den.z += __shfl_xor(den.z, off);
        den.w += __shfl_xor(den.w, off);
    }
    int h = lane >> 4;
    float dh = (h == 0) ? den.x : (h == 1) ? den.y : (h == 2) ? den.z : den.w;
    float invh = (dh > 0.f) ? 1.f / dh : 0.f;

    // Phase B: weighted aggregation, 8-deep MLP, sentinel-padded
    float a0 = 0.f, a1 = 0.f, a2 = 0.f, a3 = 0.f;
    for (int chunk = beg; chunk < end; chunk += 64) {
        if (chunk != beg) {     // restage (rare: degree > 64)
            int i = chunk + lane;
            if (i < end) {
                uint4 p = pk[perm[i]];
                float4 w4 = { h2f((unsigned short)(p.x & 0xffff)),
                              h2f((unsigned short)(p.x >> 16)),
                              h2f((unsigned short)(p.y & 0xffff)),
                              h2f((unsigned short)(p.y >> 16)) };
                s_sn[wv][lane] = (int)p.z;
                *reinterpret_cast<float4*>(&s_w[wv][lane][0]) = w4;
            } else {
                s_sn[wv][lane] = -1;
            }
        }
        int n = min(64, end - chunk);
        int npad = (n + 7) & ~7;
        for (int base = 0; base < npad; base += 8) {
#pragma unroll
            for (int j = 0; j < 8; ++j) {
                int idx = base + j;
                int sn = s_sn[wv][idx];
                float w = (sn >= 0) ? s_w[wv][idx][h] * invh : 0.f;
                int sa = (sn >= 0) ? sn : 0;
                ushort4 u = *reinterpret_cast<const ushort4*>(h_src + (size_t)sa * HN + lane * 4);
                a0 = fmaf(w, bf2f(u.x), a0);
                a1 = fmaf(w, bf2f(u.y), a1);
                a2 = fmaf(w, bf2f(u.z), a2);
                a3 = fmaf(w, bf2f(u.w), a3);
            }
        }
    }
    a0 += __shfl_xor(a0, 16); a0 += __shfl_xor(a0, 32);
    a1 += __shfl_xor(a1, 16); a1 += __shfl_xor(a1, 32);
    a2 += __shfl_xor(a2, 16); a2 += __shfl_xor(a2, 32);
    a3 += __shfl_xor(a3, 16); a3 += __shfl_xor(a3, 32);
    if (lane < 16) {
        float4 o = { fmaxf(a0 * 0.25f, 0.f), fmaxf(a1 * 0.25f, 0.f),
                     fmaxf(a2 * 0.25f, 0.f), fmaxf(a3 * 0.25f, 0.f) };
        *reinterpret_cast<float4*>(out + (size_t)d * OUT_NODE + lane * 4) = o;
    }
}

static inline char* align256(char* p) {
    return (char*)(((uintptr_t)p + 255) & ~(uintptr_t)255);
}

extern "C" void kernel_launch(void* const* d_in, const int* in_sizes, int n_in,
                              void* d_out, int out_size, void* d_ws, size_t ws_size,
                              hipStream_t stream) {
    const float* nfeats    = (const float*)d_in[0];
    const float* dst_feats = (const float*)d_in[1];
    const float* reward    = (const float*)d_in[2];
    const int*   src       = (const int*)d_in[3];
    const int*   dst       = (const int*)d_in[4];
    const float* W_ns      = (const float*)d_in[5];
    const float* b_ns      = (const float*)d_in[6];
    const float* W_ni      = (const float*)d_in[7];
    const float* W_nj      = (const float*)d_in[8];
    const float* W_fij     = (const float*)d_in[9];
    const float* attn      = (const float*)d_in[10];
    const float* b_e       = (const float*)d_in[11];
    float* out = (float*)d_out;

    const int Ns = in_sizes[0] / IN_NODE;
    const int Nd = in_sizes[1] / IN_NODE;
    const int E  = in_sizes[2];

    char* ws = (char*)d_ws;
    unsigned short* f_ni  = (unsigned short*)ws; ws = align256(ws + (size_t)Ns * HE * 2);
    unsigned short* f_nj  = (unsigned short*)ws; ws = align256(ws + (size_t)Nd * HE * 2);
    unsigned short* h_src = (unsigned short*)ws; ws = align256(ws + (size_t)Ns * HN * 2);
    float* wsum    = (float*)ws; ws = align256(ws + HE * 4);
    int*   cnt     = (int*)ws;   ws = align256(ws + (size_t)Nd * 4);
    int*   cursor  = (int*)ws;   ws = align256(ws + (size_t)Nd * 4);
    int*   row_ptr = (int*)ws;   ws = align256(ws + (size_t)(Nd + 1) * 4);
    int*   partials= (int*)ws;   ws = align256(ws + 256 * 4);
    int*   perm    = (int*)ws;   ws = align256(ws + (size_t)E * 4);
    uint4* pk      = (uint4*)ws; ws = align256(ws + (size_t)E * 16);

    // cnt and cursor are adjacent -> one memset
    hipMemsetAsync(cnt, 0, (size_t)((char*)row_ptr - (char*)cnt), stream);

    prep_wsum<<<1, 64, 0, stream>>>(W_fij, wsum);

    gemm_all<<<dim3((Ns + 63) / 64, 6), 256, 0, stream>>>(
        nfeats, dst_feats, W_ni, W_ns, W_nj, b_ns, f_ni, h_src, f_nj, Ns, Nd);

    edge_logits<<<(int)(((size_t)E * 16 + 255) / 256), 256, 0, stream>>>(
        f_ni, f_nj, src, dst, reward, wsum, b_e, attn, pk, cnt, E);

    int nb = (Nd + 1023) / 1024;
    scan1<<<nb, 256, 0, stream>>>(cnt, row_ptr, partials, Nd);
    scan2<<<1, 256, 0, stream>>>(partials, nb);
    scan3<<<(Nd + 255) / 256, 256, 0, stream>>>(row_ptr, partials, Nd, E);
    scatter_kernel<<<(E + 255) / 256, 256, 0, stream>>>(dst, row_ptr, cursor, perm, E);

    aggregate<<<(Nd + 3) / 4, 256, 0, stream>>>(h_src, pk, perm, row_ptr, out, Nd);
}

// Round 7
// 342.065 us; speedup vs baseline: 1.4192x; 1.0124x over previous
//
#include <hip/hip_runtime.h>

#define IN_NODE 128
#define OUT_NODE 64
#define OUT_EDGE 16
#define NHEAD 4
#define HN (NHEAD * OUT_NODE)  // 256
#define HE (NHEAD * OUT_EDGE)  // 64
#define LEAKY 0.01f

__device__ __forceinline__ float bf2f(unsigned short u) {
    union { unsigned u; float f; } v; v.u = ((unsigned)u) << 16; return v.f;
}
__device__ __forceinline__ unsigned short f2bf(float x) {
    union { float f; unsigned u; } v; v.f = x;
    unsigned r = v.u + 0x7FFF + ((v.u >> 16) & 1);   // RNE
    return (unsigned short)(r >> 16);
}
__device__ __forceinline__ float h2f(unsigned short u) {
    union { unsigned short u; _Float16 f; } v; v.u = u; return (float)v.f;
}
__device__ __forceinline__ unsigned short f2h(float x) {
    union { unsigned short u; _Float16 f; } v; v.f = (_Float16)x; return v.u;
}

// ---------------- wsum[k] = sum_c W_fij[c][k]  (16x64 -> 64) ----------------
__global__ void prep_wsum(const float* __restrict__ W_fij, float* __restrict__ wsum) {
    int k = threadIdx.x;
    float s = 0.f;
#pragma unroll
    for (int c = 0; c < 16; ++c) s += W_fij[c * 64 + k];
    wsum[k] = s;
}

// ------- fused GEMMs: y==0 -> f_ni, y in 1..4 -> h_src slice, y==5 -> f_nj --
__global__ __launch_bounds__(256) void gemm_all(
    const float* __restrict__ nfeats, const float* __restrict__ dst_feats,
    const float* __restrict__ W_ni, const float* __restrict__ W_ns,
    const float* __restrict__ W_nj, const float* __restrict__ b_ns,
    unsigned short* __restrict__ f_ni, unsigned short* __restrict__ h_src,
    unsigned short* __restrict__ f_nj, int Ns, int Nd)
{
    const int by = blockIdx.y;
    const float* A; const float* W; const float* bias;
    unsigned short* C; int N, colBase, M;
    if (by == 0)      { A = nfeats;    W = W_ni; bias = nullptr; C = f_ni;  N = 64;  colBase = 0;             M = Ns; }
    else if (by <= 4) { A = nfeats;    W = W_ns; bias = b_ns;    C = h_src; N = 256; colBase = (by - 1) * 64; M = Ns; }
    else              { A = dst_feats; W = W_nj; bias = nullptr; C = f_nj;  N = 64;  colBase = 0;             M = Nd; }

    __shared__ float As[64 * 68];   // [row][k], +4 pad
    __shared__ float Ws[64 * 64];   // [k][col]
    const int t = threadIdx.x;
    const int rowBase = blockIdx.x * 64;
    if (rowBase >= M) return;
    const int tr = (t >> 4) << 2;
    const int tc = (t & 15) << 2;
    float acc[4][4] = {};

    for (int kt = 0; kt < 128; kt += 64) {
#pragma unroll
        for (int i = 0; i < 4; ++i) {           // stage A row-major, float4
            int f4 = t + i * 256;
            int r = f4 >> 4;
            int kf = (f4 & 15) << 2;
            float4 v = {0.f, 0.f, 0.f, 0.f};
            int row = rowBase + r;
            if (row < M) v = *reinterpret_cast<const float4*>(A + (size_t)row * 128 + kt + kf);
            *reinterpret_cast<float4*>(As + r * 68 + kf) = v;
        }
#pragma unroll
        for (int i = 0; i < 4; ++i) {           // stage W
            int f4 = t + i * 256;
            int k = f4 >> 4;
            int cf = (f4 & 15) << 2;
            float4 v = *reinterpret_cast<const float4*>(W + (size_t)(kt + k) * N + colBase + cf);
            *reinterpret_cast<float4*>(Ws + k * 64 + cf) = v;
        }
        __syncthreads();
#pragma unroll 8
        for (int k = 0; k < 64; ++k) {
            float4 b = *reinterpret_cast<const float4*>(Ws + k * 64 + tc);
            float a0 = As[(tr + 0) * 68 + k];
            float a1 = As[(tr + 1) * 68 + k];
            float a2 = As[(tr + 2) * 68 + k];
            float a3 = As[(tr + 3) * 68 + k];
            acc[0][0] = fmaf(a0, b.x, acc[0][0]);
            acc[0][1] = fmaf(a0, b.y, acc[0][1]);
            acc[0][2] = fmaf(a0, b.z, acc[0][2]);
            acc[0][3] = fmaf(a0, b.w, acc[0][3]);
            acc[1][0] = fmaf(a1, b.x, acc[1][0]);
            acc[1][1] = fmaf(a1, b.y, acc[1][1]);
            acc[1][2] = fmaf(a1, b.z, acc[1][2]);
            acc[1][3] = fmaf(a1, b.w, acc[1][3]);
            acc[2][0] = fmaf(a2, b.x, acc[2][0]);
            acc[2][1] = fmaf(a2, b.y, acc[2][1]);
            acc[2][2] = fmaf(a2, b.z, acc[2][2]);
            acc[2][3] = fmaf(a2, b.w, acc[2][3]);
            acc[3][0] = fmaf(a3, b.x, acc[3][0]);
            acc[3][1] = fmaf(a3, b.y, acc[3][1]);
            acc[3][2] = fmaf(a3, b.z, acc[3][2]);
            acc[3][3] = fmaf(a3, b.w, acc[3][3]);
        }
        __syncthreads();
    }

    float4 bv = {0.f, 0.f, 0.f, 0.f};
    if (bias) bv = *reinterpret_cast<const float4*>(bias + colBase + tc);
#pragma unroll
    for (int i = 0; i < 4; ++i) {
        int row = rowBase + tr + i;
        if (row < M) {
            ushort4 o = { f2bf(acc[i][0] + bv.x), f2bf(acc[i][1] + bv.y),
                          f2bf(acc[i][2] + bv.z), f2bf(acc[i][3] + bv.w) };
            *reinterpret_cast<ushort4*>(C + (size_t)row * N + colBase + tc) = o;
        }
    }
}

// ---------------- histogram of dst ------------------------------------------
__global__ void hist_kernel(const int* __restrict__ dst, int* __restrict__ cnt, int E) {
    int i = blockIdx.x * 256 + threadIdx.x;
    if (i < E) atomicAdd(&cnt[dst[i]], 1);
}

// ---------------- scans for counting sort -----------------------------------
__global__ __launch_bounds__(256) void scan1(const int* __restrict__ cnt,
                                             int* __restrict__ row_ptr,
                                             int* __restrict__ partials, int n) {
    __shared__ int sums[256];
    int tid = threadIdx.x;
    int base = blockIdx.x * 1024;
    int v[4]; int tsum = 0;
#pragma unroll
    for (int j = 0; j < 4; ++j) {
        int idx = base + tid * 4 + j;
        v[j] = (idx < n) ? cnt[idx] : 0;
        tsum += v[j];
    }
    sums[tid] = tsum;
    __syncthreads();
    for (int off = 1; off < 256; off <<= 1) {
        int x = (tid >= off) ? sums[tid - off] : 0;
        __syncthreads();
        sums[tid] += x;
        __syncthreads();
    }
    int run = sums[tid] - tsum;
#pragma unroll
    for (int j = 0; j < 4; ++j) {
        int idx = base + tid * 4 + j;
        if (idx < n) row_ptr[idx] = run;
        run += v[j];
    }
    if (tid == 255) partials[blockIdx.x] = sums[255];
}

__global__ __launch_bounds__(256) void scan2(int* __restrict__ partials, int nb) {
    __shared__ int s[256];
    int tid = threadIdx.x;
    int orig = (tid < nb) ? partials[tid] : 0;
    s[tid] = orig;
    __syncthreads();
    for (int off = 1; off < 256; off <<= 1) {
        int x = (tid >= off) ? s[tid - off] : 0;
        __syncthreads();
        s[tid] += x;
        __syncthreads();
    }
    if (tid < nb) partials[tid] = s[tid] - orig;
}

__global__ void scan3(int* __restrict__ row_ptr, const int* __restrict__ partials,
                      int n, int E) {
    int i = blockIdx.x * 256 + threadIdx.x;
    if (i < n) row_ptr[i] += partials[i >> 10];
    if (i == 0) row_ptr[n] = E;
}

// ------- fused: per-edge logits -> exp -> write pk record to SORTED slot ----
// 16 lanes per edge; lane l covers features 4l..4l+3 (head h = l/4).
// pk_s[pos] = { half2(e0,e1), half2(e2,e3), src, 0 } at pos from cursor atomic.
__global__ __launch_bounds__(256) void edge_logits_scatter(
    const unsigned short* __restrict__ f_ni, const unsigned short* __restrict__ f_nj,
    const int* __restrict__ src, const int* __restrict__ dst,
    const float* __restrict__ reward, const float* __restrict__ wsum,
    const float* __restrict__ b_e, const float* __restrict__ attn,
    const int* __restrict__ row_ptr, int* __restrict__ cursor,
    uint4* __restrict__ pk_s, int E)
{
    int gid = blockIdx.x * 256 + threadIdx.x;
    int q = gid >> 4;
    if (q >= E) return;
    int lane = threadIdx.x & 63;
    int l = lane & 15;
    int sn = src[q], dn = dst[q];
    float r = reward[q];
    ushort4 ui = *reinterpret_cast<const ushort4*>(f_ni + (size_t)sn * HE + 4 * l);
    ushort4 uj = *reinterpret_cast<const ushort4*>(f_nj + (size_t)dn * HE + 4 * l);
    float4 ws = *reinterpret_cast<const float4*>(wsum + 4 * l);
    float4 be = *reinterpret_cast<const float4*>(b_e + 4 * l);
    float4 at = *reinterpret_cast<const float4*>(attn + 4 * l);
    float t = 0.f, v;
    v = bf2f(ui.x) + bf2f(uj.x) + r * ws.x + be.x; v = (v >= 0.f) ? v : LEAKY * v; t += v * at.x;
    v = bf2f(ui.y) + bf2f(uj.y) + r * ws.y + be.y; v = (v >= 0.f) ? v : LEAKY * v; t += v * at.y;
    v = bf2f(ui.z) + bf2f(uj.z) + r * ws.z + be.z; v = (v >= 0.f) ? v : LEAKY * v; t += v * at.z;
    v = bf2f(ui.w) + bf2f(uj.w) + r * ws.w + be.w; v = (v >= 0.f) ? v : LEAKY * v; t += v * at.w;
    t += __shfl_xor(t, 1);
    t += __shfl_xor(t, 2);           // lanes 4h..4h+3 hold head h's logit
    float ev = __expf(t);
    int g16 = lane & ~15;
    float e0 = __shfl(ev, g16 + 0);
    float e1 = __shfl(ev, g16 + 4);
    float e2 = __shfl(ev, g16 + 8);
    float e3 = __shfl(ev, g16 + 12);
    if (l == 0) {
        int pos = row_ptr[dn] + atomicAdd(&cursor[dn], 1);
        uint4 p;
        p.x = (unsigned)f2h(e0) | ((unsigned)f2h(e1) << 16);
        p.y = (unsigned)f2h(e2) | ((unsigned)f2h(e3) << 16);
        p.z = (unsigned)sn;
        p.w = 0u;
        pk_s[pos] = p;
    }
}

// ---------------- aggregation: one wave per dst node ------------------------
// pk_s reads are coalesced (sorted). Phase B: 8-deep MLP over h_src gathers.
__global__ __launch_bounds__(256) void aggregate(
    const unsigned short* __restrict__ h_src, const uint4* __restrict__ pk_s,
    const int* __restrict__ row_ptr, float* __restrict__ out, int Nd)
{
    __shared__ int   s_sn[4][64];
    __shared__ float s_w[4][64][4];
    int wv = threadIdx.x >> 6;
    int lane = threadIdx.x & 63;
    int d = blockIdx.x * 4 + wv;
    if (d >= Nd) return;
    int beg = row_ptr[d], end = row_ptr[d + 1];

    // Phase A: stage first 64 slots (sentinel -1 past end) + denominators
    float4 den = {0.f, 0.f, 0.f, 0.f};
    {
        int i = beg + lane;
        if (i < end) {
            uint4 p = pk_s[i];
            float e0 = h2f((unsigned short)(p.x & 0xffff));
            float e1 = h2f((unsigned short)(p.x >> 16));
            float e2 = h2f((unsigned short)(p.y & 0xffff));
            float e3 = h2f((unsigned short)(p.y >> 16));
            s_sn[wv][lane] = (int)p.z;
            float4 w4 = {e0, e1, e2, e3};
            *reinterpret_cast<float4*>(&s_w[wv][lane][0]) = w4;
            den.x += e0; den.y += e1; den.z += e2; den.w += e3;
        } else {
            s_sn[wv][lane] = -1;
        }
        for (i += 64; i < end; i += 64) {     // degree > 64 tail
            uint4 p = pk_s[i];
            den.x += h2f((unsigned short)(p.x & 0xffff));
            den.y += h2f((unsigned short)(p.x >> 16));
            den.z += h2f((unsigned short)(p.y & 0xffff));
            den.w += h2f((unsigned short)(p.y >> 16));
        }
    }
#pragma unroll
    for (int off = 1; off < 64; off <<= 1) {
        den.x += __shfl_xor(den.x, off);
        den.y += __shfl_xor(den.y, off);
        den.z += __shfl_xor(den.z, off);
        den.w += __shfl_xor(den.w, off);
    }
    int h = lane >> 4;
    float dh = (h == 0) ? den.x : (h == 1) ? den.y : (h == 2) ? den.z : den.w;
    float invh = (dh > 0.f) ? 1.f / dh : 0.f;

    // Phase B: weighted aggregation, 8-deep MLP, sentinel-padded
    float a0 = 0.f, a1 = 0.f, a2 = 0.f, a3 = 0.f;
    for (int chunk = beg; chunk < end; chunk += 64) {
        if (chunk != beg) {     // restage (rare: degree > 64)
            int i = chunk + lane;
            if (i < end) {
                uint4 p = pk_s[i];
                float4 w4 = { h2f((unsigned short)(p.x & 0xffff)),
                              h2f((unsigned short)(p.x >> 16)),
                              h2f((unsigned short)(p.y & 0xffff)),
                              h2f((unsigned short)(p.y >> 16)) };
                s_sn[wv][lane] = (int)p.z;
                *reinterpret_cast<float4*>(&s_w[wv][lane][0]) = w4;
            } else {
                s_sn[wv][lane] = -1;
            }
        }
        int n = min(64, end - chunk);
        int npad = (n + 7) & ~7;
        for (int base = 0; base < npad; base += 8) {
#pragma unroll
            for (int j = 0; j < 8; ++j) {
                int idx = base + j;
                int sn = s_sn[wv][idx];
                float w = (sn >= 0) ? s_w[wv][idx][h] * invh : 0.f;
                int sa = (sn >= 0) ? sn : 0;
                ushort4 u = *reinterpret_cast<const ushort4*>(h_src + (size_t)sa * HN + lane * 4);
                a0 = fmaf(w, bf2f(u.x), a0);
                a1 = fmaf(w, bf2f(u.y), a1);
                a2 = fmaf(w, bf2f(u.z), a2);
                a3 = fmaf(w, bf2f(u.w), a3);
            }
        }
    }
    a0 += __shfl_xor(a0, 16); a0 += __shfl_xor(a0, 32);
    a1 += __shfl_xor(a1, 16); a1 += __shfl_xor(a1, 32);
    a2 += __shfl_xor(a2, 16); a2 += __shfl_xor(a2, 32);
    a3 += __shfl_xor(a3, 16); a3 += __shfl_xor(a3, 32);
    if (lane < 16) {
        float4 o = { fmaxf(a0 * 0.25f, 0.f), fmaxf(a1 * 0.25f, 0.f),
                     fmaxf(a2 * 0.25f, 0.f), fmaxf(a3 * 0.25f, 0.f) };
        *reinterpret_cast<float4*>(out + (size_t)d * OUT_NODE + lane * 4) = o;
    }
}

static inline char* align256(char* p) {
    return (char*)(((uintptr_t)p + 255) & ~(uintptr_t)255);
}

extern "C" void kernel_launch(void* const* d_in, const int* in_sizes, int n_in,
                              void* d_out, int out_size, void* d_ws, size_t ws_size,
                              hipStream_t stream) {
    const float* nfeats    = (const float*)d_in[0];
    const float* dst_feats = (const float*)d_in[1];
    const float* reward    = (const float*)d_in[2];
    const int*   src       = (const int*)d_in[3];
    const int*   dst       = (const int*)d_in[4];
    const float* W_ns      = (const float*)d_in[5];
    const float* b_ns      = (const float*)d_in[6];
    const float* W_ni      = (const float*)d_in[7];
    const float* W_nj      = (const float*)d_in[8];
    const float* W_fij     = (const float*)d_in[9];
    const float* attn      = (const float*)d_in[10];
    const float* b_e       = (const float*)d_in[11];
    float* out = (float*)d_out;

    const int Ns = in_sizes[0] / IN_NODE;
    const int Nd = in_sizes[1] / IN_NODE;
    const int E  = in_sizes[2];

    char* ws = (char*)d_ws;
    unsigned short* f_ni  = (unsigned short*)ws; ws = align256(ws + (size_t)Ns * HE * 2);
    unsigned short* f_nj  = (unsigned short*)ws; ws = align256(ws + (size_t)Nd * HE * 2);
    unsigned short* h_src = (unsigned short*)ws; ws = align256(ws + (size_t)Ns * HN * 2);
    float* wsum    = (float*)ws; ws = align256(ws + HE * 4);
    int*   cnt     = (int*)ws;   ws = align256(ws + (size_t)Nd * 4);
    int*   cursor  = (int*)ws;   ws = align256(ws + (size_t)Nd * 4);
    int*   row_ptr = (int*)ws;   ws = align256(ws + (size_t)(Nd + 1) * 4);
    int*   partials= (int*)ws;   ws = align256(ws + 256 * 4);
    uint4* pk_s    = (uint4*)ws; ws = align256(ws + (size_t)E * 16);

    // cnt and cursor are adjacent -> one memset
    hipMemsetAsync(cnt, 0, (size_t)((char*)row_ptr - (char*)cnt), stream);

    prep_wsum<<<1, 64, 0, stream>>>(W_fij, wsum);

    // hist + scans can run before/while GEMM output is needed only later
    hist_kernel<<<(E + 255) / 256, 256, 0, stream>>>(dst, cnt, E);
    int nb = (Nd + 1023) / 1024;
    scan1<<<nb, 256, 0, stream>>>(cnt, row_ptr, partials, Nd);
    scan2<<<1, 256, 0, stream>>>(partials, nb);
    scan3<<<(Nd + 255) / 256, 256, 0, stream>>>(row_ptr, partials, Nd, E);

    gemm_all<<<dim3((Ns + 63) / 64, 6), 256, 0, stream>>>(
        nfeats, dst_feats, W_ni, W_ns, W_nj, b_ns, f_ni, h_src, f_nj, Ns, Nd);

    edge_logits_scatter<<<(int)(((size_t)E * 16 + 255) / 256), 256, 0, stream>>>(
        f_ni, f_nj, src, dst, reward, wsum, b_e, attn, row_ptr, cursor, pk_s, E);

    aggregate<<<(Nd + 3) / 4, 256, 0, stream>>>(h_src, pk_s, row_ptr, out, Nd);
}

// Round 8
// 333.786 us; speedup vs baseline: 1.4544x; 1.0248x over previous
//
#include <hip/hip_runtime.h>

#define IN_NODE 128
#define OUT_NODE 64
#define OUT_EDGE 16
#define NHEAD 4
#define HN (NHEAD * OUT_NODE)  // 256
#define HE (NHEAD * OUT_EDGE)  // 64
#define LEAKY 0.01f
#define MAXD 96                // cached slots per wave in fused aggregate

typedef __attribute__((ext_vector_type(8))) short bf16x8;
typedef __attribute__((ext_vector_type(4))) float f32x4;

__device__ __forceinline__ float bf2f(unsigned short u) {
    union { unsigned u; float f; } v; v.u = ((unsigned)u) << 16; return v.f;
}
__device__ __forceinline__ unsigned short f2bf(float x) {
    union { float f; unsigned u; } v; v.f = x;
    unsigned r = v.u + 0x7FFF + ((v.u >> 16) & 1);   // RNE
    return (unsigned short)(r >> 16);
}

// ------ prep: wsum (block 0) + W->WT bf16 transposes (blocks 1..12) + hist --
// WT layout: [0,8192) WT_ni[n][k] n<64; [8192,40960) WT_ns[n][k] n<256;
//            [40960,49152) WT_nj[n][k] n<64.   (k = 128)
__global__ void prep_hist(const float* __restrict__ W_fij,
                          const float* __restrict__ W_ni,
                          const float* __restrict__ W_ns,
                          const float* __restrict__ W_nj,
                          const int* __restrict__ dst,
                          float* __restrict__ wsum, unsigned short* __restrict__ WT,
                          int* __restrict__ cnt, int E) {
    int b = blockIdx.x;
    if (b == 0) {
        int k = threadIdx.x;
        if (k < 64) {
            float s = 0.f;
#pragma unroll
            for (int c = 0; c < 16; ++c) s += W_fij[c * 64 + k];
            wsum[k] = s;
        }
        return;
    }
    if (b <= 12) {
        int base = (b - 1) * 4096 + threadIdx.x;
#pragma unroll
        for (int i = 0; i < 16; ++i) {
            int idx = base + i * 256;
            unsigned short v;
            if (idx < 8192)      { int n = idx >> 7, k = idx & 127; v = f2bf(W_ni[k * 64 + n]); }
            else if (idx < 40960){ int j = idx - 8192;  int n = j >> 7, k = j & 127; v = f2bf(W_ns[k * 256 + n]); }
            else                 { int j = idx - 40960; int n = j >> 7, k = j & 127; v = f2bf(W_nj[k * 64 + n]); }
            WT[idx] = v;
        }
        return;
    }
    int i = (b - 13) * 256 + threadIdx.x;
    if (i < E) atomicAdd(&cnt[dst[i]], 1);
}

// ---------------- MFMA GEMM, no LDS ----------------------------------------
// grid.y: 0 -> f_ni, 1..4 -> h_src col-slice, 5 -> f_nj. Wave = 16 rows x 64 cols.
// A-frag: A[m=lane&15][k=q*8+j] direct from global fp32 (2x float4, cvt bf16).
// B-frag: WT[n=lane&15][k=q*8+j] one 16B load.
// C/D: col=lane&15, row=q*4+reg.
__device__ __forceinline__ bf16x8 cvt8(float4 a, float4 b) {
    bf16x8 r;
    r[0] = (short)f2bf(a.x); r[1] = (short)f2bf(a.y);
    r[2] = (short)f2bf(a.z); r[3] = (short)f2bf(a.w);
    r[4] = (short)f2bf(b.x); r[5] = (short)f2bf(b.y);
    r[6] = (short)f2bf(b.z); r[7] = (short)f2bf(b.w);
    return r;
}

__global__ __launch_bounds__(256) void gemm_mfma(
    const float* __restrict__ nfeats, const float* __restrict__ dst_feats,
    const unsigned short* __restrict__ WT, const float* __restrict__ b_ns,
    unsigned short* __restrict__ f_ni, unsigned short* __restrict__ h_src,
    unsigned short* __restrict__ f_nj, int Ns, int Nd)
{
    const int gy = blockIdx.y;
    const float* A; const unsigned short* wt; const float* bias = nullptr;
    unsigned short* C; int M, N, colBase;
    if (gy == 0)      { A = nfeats;    wt = WT;         C = f_ni;  M = Ns; N = 64;  colBase = 0; }
    else if (gy <= 4) { A = nfeats;    wt = WT + 8192;  C = h_src; M = Ns; N = 256; colBase = (gy - 1) * 64; bias = b_ns; }
    else              { A = dst_feats; wt = WT + 40960; C = f_nj;  M = Nd; N = 64;  colBase = 0; }

    const int w = threadIdx.x >> 6, lane = threadIdx.x & 63;
    const int rowW = blockIdx.x * 64 + w * 16;
    if (rowW >= M) return;
    const int m = lane & 15, q = lane >> 4;
    int lrow = rowW + m; if (lrow >= M) lrow = M - 1;    // clamp (stores guarded)
    const float* arow = A + (size_t)lrow * 128 + q * 8;

    f32x4 acc0 = {}, acc1 = {}, acc2 = {}, acc3 = {};
#pragma unroll
    for (int kc = 0; kc < 128; kc += 32) {
        float4 a0 = *reinterpret_cast<const float4*>(arow + kc);
        float4 a1 = *reinterpret_cast<const float4*>(arow + kc + 4);
        bf16x8 af = cvt8(a0, a1);
        const unsigned short* bp = wt + (size_t)(colBase + m) * 128 + kc + q * 8;
        bf16x8 b0 = *reinterpret_cast<const bf16x8*>(bp);
        bf16x8 b1 = *reinterpret_cast<const bf16x8*>(bp + 16 * 128);
        bf16x8 b2 = *reinterpret_cast<const bf16x8*>(bp + 32 * 128);
        bf16x8 b3 = *reinterpret_cast<const bf16x8*>(bp + 48 * 128);
        acc0 = __builtin_amdgcn_mfma_f32_16x16x32_bf16(af, b0, acc0, 0, 0, 0);
        acc1 = __builtin_amdgcn_mfma_f32_16x16x32_bf16(af, b1, acc1, 0, 0, 0);
        acc2 = __builtin_amdgcn_mfma_f32_16x16x32_bf16(af, b2, acc2, 0, 0, 0);
        acc3 = __builtin_amdgcn_mfma_f32_16x16x32_bf16(af, b3, acc3, 0, 0, 0);
    }

#pragma unroll
    for (int f = 0; f < 4; ++f) {
        f32x4 a = (f == 0) ? acc0 : (f == 1) ? acc1 : (f == 2) ? acc2 : acc3;
        int col = colBase + f * 16 + m;
        float bv = bias ? bias[col] : 0.f;
#pragma unroll
        for (int r = 0; r < 4; ++r) {
            int orow = rowW + q * 4 + r;
            if (orow < M) C[(size_t)orow * N + col] = f2bf(a[r] + bv);
        }
    }
}

// ---------------- scans for counting sort -----------------------------------
__global__ __launch_bounds__(256) void scan1(const int* __restrict__ cnt,
                                             int* __restrict__ row_ptr,
                                             int* __restrict__ partials, int n) {
    __shared__ int sums[256];
    int tid = threadIdx.x;
    int base = blockIdx.x * 1024;
    int v[4]; int tsum = 0;
#pragma unroll
    for (int j = 0; j < 4; ++j) {
        int idx = base + tid * 4 + j;
        v[j] = (idx < n) ? cnt[idx] : 0;
        tsum += v[j];
    }
    sums[tid] = tsum;
    __syncthreads();
    for (int off = 1; off < 256; off <<= 1) {
        int x = (tid >= off) ? sums[tid - off] : 0;
        __syncthreads();
        sums[tid] += x;
        __syncthreads();
    }
    int run = sums[tid] - tsum;
#pragma unroll
    for (int j = 0; j < 4; ++j) {
        int idx = base + tid * 4 + j;
        if (idx < n) row_ptr[idx] = run;
        run += v[j];
    }
    if (tid == 255) partials[blockIdx.x] = sums[255];
}

__global__ __launch_bounds__(256) void scan2(int* __restrict__ partials, int nb) {
    __shared__ int s[256];
    int tid = threadIdx.x;
    int orig = (tid < nb) ? partials[tid] : 0;
    s[tid] = orig;
    __syncthreads();
    for (int off = 1; off < 256; off <<= 1) {
        int x = (tid >= off) ? s[tid - off] : 0;
        __syncthreads();
        s[tid] += x;
        __syncthreads();
    }
    if (tid < nb) partials[tid] = s[tid] - orig;
}

// ---------------- scatter: (src,reward) into sorted slot --------------------
__global__ void scatter_kernel(const int* __restrict__ src, const int* __restrict__ dst,
                               const float* __restrict__ reward,
                               const int* __restrict__ row_ptr,
                               const int* __restrict__ partials,
                               int* __restrict__ cursor, int2* __restrict__ sr_s, int E) {
    int i = blockIdx.x * 256 + threadIdx.x;
    if (i >= E) return;
    int d = dst[i];
    int pos = row_ptr[d] + partials[d >> 10] + atomicAdd(&cursor[d], 1);
    sr_s[pos] = make_int2(src[i], __float_as_int(reward[i]));
}

// ------- fused logits + softmax + aggregation: one wave per dst -------------
// Phase 1: 4 edges in parallel (16 lanes each, lane l covers edge-features
// 4l..4l+3, head=l>>2); exps+src cached in LDS, per-head denominators in regs.
// Phase 2: weighted h_src gather (lane covers out-features 4*lane, head=lane>>4).
__global__ __launch_bounds__(256) void fused_agg(
    const unsigned short* __restrict__ f_ni, const unsigned short* __restrict__ f_nj,
    const unsigned short* __restrict__ h_src, const int2* __restrict__ sr_s,
    const int* __restrict__ row_ptr, const int* __restrict__ partials,
    const float* __restrict__ wsum, const float* __restrict__ b_e,
    const float* __restrict__ attn, float* __restrict__ out, int Nd, int E)
{
    __shared__ float s_e[4][MAXD][4];
    __shared__ int   s_sn[4][MAXD];
    const int wv = threadIdx.x >> 6, lane = threadIdx.x & 63;
    const int d = blockIdx.x * 4 + wv;
    if (d >= Nd) return;
    const int l = lane & 15, sub = lane >> 4;
    const int beg = row_ptr[d] + partials[d >> 10];
    const int end = (d + 1 < Nd) ? row_ptr[d + 1] + partials[(d + 1) >> 10] : E;

    for (int i = lane; i < MAXD; i += 64) s_sn[wv][i] = -1;  // sentinel pad

    ushort4 uj = *reinterpret_cast<const ushort4*>(f_nj + (size_t)d * HE + 4 * l);
    float4 fnj = { bf2f(uj.x), bf2f(uj.y), bf2f(uj.z), bf2f(uj.w) };
    float4 ws = *reinterpret_cast<const float4*>(wsum + 4 * l);
    float4 be = *reinterpret_cast<const float4*>(b_e + 4 * l);
    float4 at = *reinterpret_cast<const float4*>(attn + 4 * l);

    float den = 0.f;
    for (int base = beg; base < end; base += 4) {
        int slot = base + sub;
        if (slot < end) {
            int2 sr = sr_s[slot];
            int sn = sr.x;
            float r = __int_as_float(sr.y);
            ushort4 ui = *reinterpret_cast<const ushort4*>(f_ni + (size_t)sn * HE + 4 * l);
            float t, v;
            v = bf2f(ui.x) + fnj.x + r * ws.x + be.x; v = (v >= 0.f) ? v : LEAKY * v; t  = v * at.x;
            v = bf2f(ui.y) + fnj.y + r * ws.y + be.y; v = (v >= 0.f) ? v : LEAKY * v; t += v * at.y;
            v = bf2f(ui.z) + fnj.z + r * ws.z + be.z; v = (v >= 0.f) ? v : LEAKY * v; t += v * at.z;
            v = bf2f(ui.w) + fnj.w + r * ws.w + be.w; v = (v >= 0.f) ? v : LEAKY * v; t += v * at.w;
            t += __shfl_xor(t, 1);
            t += __shfl_xor(t, 2);          // lanes 4h..4h+3 of subgroup hold head h logit
            float ev = __expf(t);
            den += ev;
            int idx = slot - beg;
            if (idx < MAXD) {
                if ((l & 3) == 0) s_e[wv][idx][l >> 2] = ev;
                if (l == 0) s_sn[wv][idx] = sn;
            }
        }
    }
    den += __shfl_xor(den, 16);
    den += __shfl_xor(den, 32);             // total for head (l>>2), all subgroups
    float dh = __shfl(den, (lane >> 4) << 2);   // head lane>>4's denominator
    float invh = (dh > 0.f) ? 1.f / dh : 0.f;
    const int h = lane >> 4;

    float a0 = 0.f, a1 = 0.f, a2 = 0.f, a3 = 0.f;
    int cap = min(end - beg, MAXD);
    int npad = (cap + 7) & ~7;
    for (int idx0 = 0; idx0 < npad; idx0 += 8) {
#pragma unroll
        for (int j = 0; j < 8; ++j) {
            int idx = idx0 + j;
            int sn = s_sn[wv][idx];
            float wgt = (sn >= 0) ? s_e[wv][idx][h] * invh : 0.f;
            int sa = (sn >= 0) ? sn : 0;
            ushort4 u = *reinterpret_cast<const ushort4*>(h_src + (size_t)sa * HN + lane * 4);
            a0 = fmaf(wgt, bf2f(u.x), a0);
            a1 = fmaf(wgt, bf2f(u.y), a1);
            a2 = fmaf(wgt, bf2f(u.z), a2);
            a3 = fmaf(wgt, bf2f(u.w), a3);
        }
    }
    // overflow tail (degree > MAXD): recompute logits serially (cold path)
    for (int slot = beg + MAXD; slot < end; ++slot) {
        int2 sr = sr_s[slot];
        int sn = sr.x;
        float r = __int_as_float(sr.y);
        float v = bf2f(f_ni[(size_t)sn * HE + lane]) + bf2f(f_nj[(size_t)d * HE + lane])
                + r * wsum[lane] + b_e[lane];
        v = (v >= 0.f) ? v : LEAKY * v;
        float t = v * attn[lane];
        t += __shfl_xor(t, 1);
        t += __shfl_xor(t, 2);
        t += __shfl_xor(t, 4);
        t += __shfl_xor(t, 8);
        float wgt = __expf(t) * invh;
        ushort4 u = *reinterpret_cast<const ushort4*>(h_src + (size_t)sn * HN + lane * 4);
        a0 = fmaf(wgt, bf2f(u.x), a0);
        a1 = fmaf(wgt, bf2f(u.y), a1);
        a2 = fmaf(wgt, bf2f(u.z), a2);
        a3 = fmaf(wgt, bf2f(u.w), a3);
    }

    a0 += __shfl_xor(a0, 16); a0 += __shfl_xor(a0, 32);
    a1 += __shfl_xor(a1, 16); a1 += __shfl_xor(a1, 32);
    a2 += __shfl_xor(a2, 16); a2 += __shfl_xor(a2, 32);
    a3 += __shfl_xor(a3, 16); a3 += __shfl_xor(a3, 32);
    if (lane < 16) {
        float4 o = { fmaxf(a0 * 0.25f, 0.f), fmaxf(a1 * 0.25f, 0.f),
                     fmaxf(a2 * 0.25f, 0.f), fmaxf(a3 * 0.25f, 0.f) };
        *reinterpret_cast<float4*>(out + (size_t)d * OUT_NODE + lane * 4) = o;
    }
}

static inline char* align256(char* p) {
    return (char*)(((uintptr_t)p + 255) & ~(uintptr_t)255);
}

extern "C" void kernel_launch(void* const* d_in, const int* in_sizes, int n_in,
                              void* d_out, int out_size, void* d_ws, size_t ws_size,
                              hipStream_t stream) {
    const float* nfeats    = (const float*)d_in[0];
    const float* dst_feats = (const float*)d_in[1];
    const float* reward    = (const float*)d_in[2];
    const int*   src       = (const int*)d_in[3];
    const int*   dst       = (const int*)d_in[4];
    const float* W_ns      = (const float*)d_in[5];
    const float* b_ns      = (const float*)d_in[6];
    const float* W_ni      = (const float*)d_in[7];
    const float* W_nj      = (const float*)d_in[8];
    const float* W_fij     = (const float*)d_in[9];
    const float* attn      = (const float*)d_in[10];
    const float* b_e       = (const float*)d_in[11];
    float* out = (float*)d_out;

    const int Ns = in_sizes[0] / IN_NODE;
    const int Nd = in_sizes[1] / IN_NODE;
    const int E  = in_sizes[2];

    char* ws = (char*)d_ws;
    unsigned short* f_ni  = (unsigned short*)ws; ws = align256(ws + (size_t)Ns * HE * 2);
    unsigned short* f_nj  = (unsigned short*)ws; ws = align256(ws + (size_t)Nd * HE * 2);
    unsigned short* h_src = (unsigned short*)ws; ws = align256(ws + (size_t)Ns * HN * 2);
    unsigned short* WT    = (unsigned short*)ws; ws = align256(ws + 49152 * 2);
    float* wsum    = (float*)ws; ws = align256(ws + HE * 4);
    int*   cnt     = (int*)ws;   ws = align256(ws + (size_t)Nd * 4);
    int*   cursor  = (int*)ws;   ws = align256(ws + (size_t)Nd * 4);
    int*   row_ptr = (int*)ws;   ws = align256(ws + (size_t)(Nd + 1) * 4);
    int*   partials= (int*)ws;   ws = align256(ws + 256 * 4);
    int2*  sr_s    = (int2*)ws;  ws = align256(ws + (size_t)E * 8);

    // cnt and cursor adjacent -> one memset
    hipMemsetAsync(cnt, 0, (size_t)((char*)row_ptr - (char*)cnt), stream);

    prep_hist<<<13 + (E + 255) / 256, 256, 0, stream>>>(
        W_fij, W_ni, W_ns, W_nj, dst, wsum, WT, cnt, E);

    int nb = (Nd + 1023) / 1024;
    scan1<<<nb, 256, 0, stream>>>(cnt, row_ptr, partials, Nd);
    scan2<<<1, 256, 0, stream>>>(partials, nb);

    scatter_kernel<<<(E + 255) / 256, 256, 0, stream>>>(
        src, dst, reward, row_ptr, partials, cursor, sr_s, E);

    int Mmax = (Ns > Nd) ? Ns : Nd;
    gemm_mfma<<<dim3((Mmax + 63) / 64, 6), 256, 0, stream>>>(
        nfeats, dst_feats, WT, b_ns, f_ni, h_src, f_nj, Ns, Nd);

    fused_agg<<<(Nd + 3) / 4, 256, 0, stream>>>(
        f_ni, f_nj, h_src, sr_s, row_ptr, partials, wsum, b_e, attn, out, Nd, E);
}

// Round 10
// 318.746 us; speedup vs baseline: 1.5230x; 1.0472x over previous
//
#include <hip/hip_runtime.h>

#define IN_NODE 128
#define OUT_NODE 64
#define NHEAD 4
#define HN 256                 // NHEAD * OUT_NODE
#define HE 64                  // NHEAD * OUT_EDGE
#define LEAKY 0.01f
#define MAXD 96                // cached slots per wave in fused aggregate

typedef __attribute__((ext_vector_type(8))) short bf16x8;
typedef __attribute__((ext_vector_type(4))) float f32x4;

__device__ __forceinline__ float bf2f(unsigned short u) {
    union { unsigned u; float f; } v; v.u = ((unsigned)u) << 16; return v.f;
}
__device__ __forceinline__ unsigned short f2bf(float x) {
    union { float f; unsigned u; } v; v.f = x;
    unsigned r = v.u + 0x7FFF + ((v.u >> 16) & 1);   // RNE
    return (unsigned short)(r >> 16);
}
__device__ __forceinline__ bf16x8 cvt8(float4 a, float4 b) {
    bf16x8 r;
    r[0] = (short)f2bf(a.x); r[1] = (short)f2bf(a.y);
    r[2] = (short)f2bf(a.z); r[3] = (short)f2bf(a.w);
    r[4] = (short)f2bf(b.x); r[5] = (short)f2bf(b.y);
    r[6] = (short)f2bf(b.z); r[7] = (short)f2bf(b.w);
    return r;
}

// ------ prep: wsum (block 0) + W->WT bf16 transposes (blocks 1..12) + hist --
// WT layout: [0,8192) WT_ni[n][k] n<64; [8192,40960) WT_ns[n][k] n<256;
//            [40960,49152) WT_nj[n][k] n<64.   (k = 128)
__global__ void prep_hist(const float* __restrict__ W_fij,
                          const float* __restrict__ W_ni,
                          const float* __restrict__ W_ns,
                          const float* __restrict__ W_nj,
                          const int* __restrict__ dst,
                          float* __restrict__ wsum, unsigned short* __restrict__ WT,
                          int* __restrict__ cnt, int E) {
    int b = blockIdx.x;
    if (b == 0) {
        int k = threadIdx.x;
        if (k < 64) {
            float s = 0.f;
#pragma unroll
            for (int c = 0; c < 16; ++c) s += W_fij[c * 64 + k];
            wsum[k] = s;
        }
        return;
    }
    if (b <= 12) {
        int base = (b - 1) * 4096 + threadIdx.x;
#pragma unroll
        for (int i = 0; i < 16; ++i) {
            int idx = base + i * 256;
            unsigned short v;
            if (idx < 8192)      { int n = idx >> 7, k = idx & 127; v = f2bf(W_ni[k * 64 + n]); }
            else if (idx < 40960){ int j = idx - 8192;  int n = j >> 7, k = j & 127; v = f2bf(W_ns[k * 256 + n]); }
            else                 { int j = idx - 40960; int n = j >> 7, k = j & 127; v = f2bf(W_nj[k * 64 + n]); }
            WT[idx] = v;
        }
        return;
    }
    int i = (b - 13) * 256 + threadIdx.x;
    if (i < E) atomicAdd(&cnt[dst[i]], 1);
}

// ---------------- scan1: per-1024-chunk exclusive prefix + chunk sums -------
__global__ __launch_bounds__(256) void scan1(const int* __restrict__ cnt,
                                             int* __restrict__ row_ptr,
                                             int* __restrict__ partials, int n) {
    __shared__ int sums[256];
    int tid = threadIdx.x;
    int base = blockIdx.x * 1024;
    int v[4]; int tsum = 0;
#pragma unroll
    for (int j = 0; j < 4; ++j) {
        int idx = base + tid * 4 + j;
        v[j] = (idx < n) ? cnt[idx] : 0;
        tsum += v[j];
    }
    sums[tid] = tsum;
    __syncthreads();
    for (int off = 1; off < 256; off <<= 1) {
        int x = (tid >= off) ? sums[tid - off] : 0;
        __syncthreads();
        sums[tid] += x;
        __syncthreads();
    }
    int run = sums[tid] - tsum;
#pragma unroll
    for (int j = 0; j < 4; ++j) {
        int idx = base + tid * 4 + j;
        if (idx < n) row_ptr[idx] = run;
        run += v[j];
    }
    if (tid == 255) partials[blockIdx.x] = sums[255];
}

// ---------------- scan2: exclusive scan of chunk sums (in place) ------------
__global__ __launch_bounds__(256) void scan2(int* __restrict__ partials, int nb) {
    __shared__ int s[256];
    int tid = threadIdx.x;
    int orig = (tid < nb) ? partials[tid] : 0;
    s[tid] = orig;
    __syncthreads();
    for (int off = 1; off < 256; off <<= 1) {
        int x = (tid >= off) ? s[tid - off] : 0;
        __syncthreads();
        s[tid] += x;
        __syncthreads();
    }
    if (tid < nb) partials[tid] = s[tid] - orig;
}

// ---------------- mega: R8 gemm_mfma + R8 scatter in one dispatch -----------
// blocks [0, nG): gemm, gy = bid % 6, bx = bid / 6 (R8 semantics verbatim)
//   gy: 0 -> f_ni, 1..4 -> h_src col-slice, 5 -> f_nj. Wave = 16 rows x 64 cols.
// blocks [nG, ...): scatter (src,reward) into sorted slot (partials exclusive)
__global__ __launch_bounds__(256) void mega(
    const float* __restrict__ nfeats, const float* __restrict__ dst_feats,
    const unsigned short* __restrict__ WT, const float* __restrict__ b_ns,
    const int* __restrict__ src, const int* __restrict__ dst,
    const float* __restrict__ reward, const int* __restrict__ row_ptr,
    const int* __restrict__ partials, int* __restrict__ cursor,
    unsigned short* __restrict__ f_ni, unsigned short* __restrict__ h_src,
    unsigned short* __restrict__ f_nj, int2* __restrict__ sr_s,
    int Ns, int Nd, int E, int nG)
{
    const int bid = blockIdx.x;
    if (bid < nG) {                             // ---- GEMM part (R8 verbatim) ----
        const int gy = bid % 6;
        const int bx = bid / 6;
        const float* A; const unsigned short* wt; const float* bias = nullptr;
        unsigned short* C; int M, N, colBase;
        if (gy == 0)      { A = nfeats;    wt = WT;         C = f_ni;  M = Ns; N = 64;  colBase = 0; }
        else if (gy <= 4) { A = nfeats;    wt = WT + 8192;  C = h_src; M = Ns; N = 256; colBase = (gy - 1) * 64; bias = b_ns; }
        else              { A = dst_feats; wt = WT + 40960; C = f_nj;  M = Nd; N = 64;  colBase = 0; }

        const int w = threadIdx.x >> 6, lane = threadIdx.x & 63;
        const int rowW = bx * 64 + w * 16;
        if (rowW >= M) return;
        const int m = lane & 15, q = lane >> 4;
        int lrow = rowW + m; if (lrow >= M) lrow = M - 1;    // clamp (stores guarded)
        const float* arow = A + (size_t)lrow * 128 + q * 8;

        f32x4 acc0 = {}, acc1 = {}, acc2 = {}, acc3 = {};
#pragma unroll
        for (int kc = 0; kc < 128; kc += 32) {
            float4 a0 = *reinterpret_cast<const float4*>(arow + kc);
            float4 a1 = *reinterpret_cast<const float4*>(arow + kc + 4);
            bf16x8 af = cvt8(a0, a1);
            const unsigned short* bp = wt + (size_t)(colBase + m) * 128 + kc + q * 8;
            bf16x8 b0 = *reinterpret_cast<const bf16x8*>(bp);
            bf16x8 b1 = *reinterpret_cast<const bf16x8*>(bp + 16 * 128);
            bf16x8 b2 = *reinterpret_cast<const bf16x8*>(bp + 32 * 128);
            bf16x8 b3 = *reinterpret_cast<const bf16x8*>(bp + 48 * 128);
            acc0 = __builtin_amdgcn_mfma_f32_16x16x32_bf16(af, b0, acc0, 0, 0, 0);
            acc1 = __builtin_amdgcn_mfma_f32_16x16x32_bf16(af, b1, acc1, 0, 0, 0);
            acc2 = __builtin_amdgcn_mfma_f32_16x16x32_bf16(af, b2, acc2, 0, 0, 0);
            acc3 = __builtin_amdgcn_mfma_f32_16x16x32_bf16(af, b3, acc3, 0, 0, 0);
        }

#pragma unroll
        for (int f = 0; f < 4; ++f) {
            f32x4 a = (f == 0) ? acc0 : (f == 1) ? acc1 : (f == 2) ? acc2 : acc3;
            int col = colBase + f * 16 + m;
            float bv = bias ? bias[col] : 0.f;
#pragma unroll
            for (int r = 0; r < 4; ++r) {
                int orow = rowW + q * 4 + r;
                if (orow < M) C[(size_t)orow * N + col] = f2bf(a[r] + bv);
            }
        }
        return;
    }
    // ---- scatter part (R8 verbatim) ----
    int i = (bid - nG) * 256 + threadIdx.x;
    if (i >= E) return;
    int d = dst[i];
    int pos = row_ptr[d] + partials[d >> 10] + atomicAdd(&cursor[d], 1);
    sr_s[pos] = make_int2(src[i], __float_as_int(reward[i]));
}

// ------- fused logits + softmax + aggregation (R8 verbatim) -----------------
__global__ __launch_bounds__(256) void fused_agg(
    const unsigned short* __restrict__ f_ni, const unsigned short* __restrict__ f_nj,
    const unsigned short* __restrict__ h_src, const int2* __restrict__ sr_s,
    const int* __restrict__ row_ptr, const int* __restrict__ partials,
    const float* __restrict__ wsum, const float* __restrict__ b_e,
    const float* __restrict__ attn, float* __restrict__ out, int Nd, int E)
{
    __shared__ float s_e[4][MAXD][4];
    __shared__ int   s_sn[4][MAXD];
    const int wv = threadIdx.x >> 6, lane = threadIdx.x & 63;
    const int d = blockIdx.x * 4 + wv;
    if (d >= Nd) return;
    const int l = lane & 15, sub = lane >> 4;
    const int beg = row_ptr[d] + partials[d >> 10];
    const int end = (d + 1 < Nd) ? row_ptr[d + 1] + partials[(d + 1) >> 10] : E;

    for (int i = lane; i < MAXD; i += 64) s_sn[wv][i] = -1;  // sentinel pad

    ushort4 uj = *reinterpret_cast<const ushort4*>(f_nj + (size_t)d * HE + 4 * l);
    float4 fnj = { bf2f(uj.x), bf2f(uj.y), bf2f(uj.z), bf2f(uj.w) };
    float4 ws = *reinterpret_cast<const float4*>(wsum + 4 * l);
    float4 be = *reinterpret_cast<const float4*>(b_e + 4 * l);
    float4 at = *reinterpret_cast<const float4*>(attn + 4 * l);

    float den = 0.f;
    for (int base = beg; base < end; base += 4) {
        int slot = base + sub;
        if (slot < end) {
            int2 sr = sr_s[slot];
            int sn = sr.x;
            float r = __int_as_float(sr.y);
            ushort4 ui = *reinterpret_cast<const ushort4*>(f_ni + (size_t)sn * HE + 4 * l);
            float t, v;
            v = bf2f(ui.x) + fnj.x + r * ws.x + be.x; v = (v >= 0.f) ? v : LEAKY * v; t  = v * at.x;
            v = bf2f(ui.y) + fnj.y + r * ws.y + be.y; v = (v >= 0.f) ? v : LEAKY * v; t += v * at.y;
            v = bf2f(ui.z) + fnj.z + r * ws.z + be.z; v = (v >= 0.f) ? v : LEAKY * v; t += v * at.z;
            v = bf2f(ui.w) + fnj.w + r * ws.w + be.w; v = (v >= 0.f) ? v : LEAKY * v; t += v * at.w;
            t += __shfl_xor(t, 1);
            t += __shfl_xor(t, 2);          // lanes 4h..4h+3 of subgroup hold head h logit
            float ev = __expf(t);
            den += ev;
            int idx = slot - beg;
            if (idx < MAXD) {
                if ((l & 3) == 0) s_e[wv][idx][l >> 2] = ev;
                if (l == 0) s_sn[wv][idx] = sn;
            }
        }
    }
    den += __shfl_xor(den, 16);
    den += __shfl_xor(den, 32);             // total for head (l>>2), all subgroups
    float dh = __shfl(den, (lane >> 4) << 2);   // head lane>>4's denominator
    float invh = (dh > 0.f) ? 1.f / dh : 0.f;
    const int h = lane >> 4;

    float a0 = 0.f, a1 = 0.f, a2 = 0.f, a3 = 0.f;
    int cap = min(end - beg, MAXD);
    int npad = (cap + 7) & ~7;
    for (int idx0 = 0; idx0 < npad; idx0 += 8) {
#pragma unroll
        for (int j = 0; j < 8; ++j) {
            int idx = idx0 + j;
            int sn = s_sn[wv][idx];
            float wgt = (sn >= 0) ? s_e[wv][idx][h] * invh : 0.f;
            int sa = (sn >= 0) ? sn : 0;
            ushort4 u = *reinterpret_cast<const ushort4*>(h_src + (size_t)sa * HN + lane * 4);
            a0 = fmaf(wgt, bf2f(u.x), a0);
            a1 = fmaf(wgt, bf2f(u.y), a1);
            a2 = fmaf(wgt, bf2f(u.z), a2);
            a3 = fmaf(wgt, bf2f(u.w), a3);
        }
    }
    // overflow tail (degree > MAXD): recompute logits serially (cold path)
    for (int slot = beg + MAXD; slot < end; ++slot) {
        int2 sr = sr_s[slot];
        int sn = sr.x;
        float r = __int_as_float(sr.y);
        float v = bf2f(f_ni[(size_t)sn * HE + lane]) + bf2f(f_nj[(size_t)d * HE + lane])
                + r * wsum[lane] + b_e[lane];
        v = (v >= 0.f) ? v : LEAKY * v;
        float t = v * attn[lane];
        t += __shfl_xor(t, 1);
        t += __shfl_xor(t, 2);
        t += __shfl_xor(t, 4);
        t += __shfl_xor(t, 8);
        float wgt = __expf(t) * invh;
        ushort4 u = *reinterpret_cast<const ushort4*>(h_src + (size_t)sn * HN + lane * 4);
        a0 = fmaf(wgt, bf2f(u.x), a0);
        a1 = fmaf(wgt, bf2f(u.y), a1);
        a2 = fmaf(wgt, bf2f(u.z), a2);
        a3 = fmaf(wgt, bf2f(u.w), a3);
    }

    a0 += __shfl_xor(a0, 16); a0 += __shfl_xor(a0, 32);
    a1 += __shfl_xor(a1, 16); a1 += __shfl_xor(a1, 32);
    a2 += __shfl_xor(a2, 16); a2 += __shfl_xor(a2, 32);
    a3 += __shfl_xor(a3, 16); a3 += __shfl_xor(a3, 32);
    if (lane < 16) {
        float4 o = { fmaxf(a0 * 0.25f, 0.f), fmaxf(a1 * 0.25f, 0.f),
                     fmaxf(a2 * 0.25f, 0.f), fmaxf(a3 * 0.25f, 0.f) };
        *reinterpret_cast<float4*>(out + (size_t)d * OUT_NODE + lane * 4) = o;
    }
}

static inline char* align256(char* p) {
    return (char*)(((uintptr_t)p + 255) & ~(uintptr_t)255);
}

extern "C" void kernel_launch(void* const* d_in, const int* in_sizes, int n_in,
                              void* d_out, int out_size, void* d_ws, size_t ws_size,
                              hipStream_t stream) {
    const float* nfeats    = (const float*)d_in[0];
    const float* dst_feats = (const float*)d_in[1];
    const float* reward    = (const float*)d_in[2];
    const int*   src       = (const int*)d_in[3];
    const int*   dst       = (const int*)d_in[4];
    const float* W_ns      = (const float*)d_in[5];
    const float* b_ns      = (const float*)d_in[6];
    const float* W_ni      = (const float*)d_in[7];
    const float* W_nj      = (const float*)d_in[8];
    const float* W_fij     = (const float*)d_in[9];
    const float* attn      = (const float*)d_in[10];
    const float* b_e       = (const float*)d_in[11];
    float* out = (float*)d_out;

    const int Ns = in_sizes[0] / IN_NODE;
    const int Nd = in_sizes[1] / IN_NODE;
    const int E  = in_sizes[2];

    char* ws = (char*)d_ws;
    unsigned short* f_ni  = (unsigned short*)ws; ws = align256(ws + (size_t)Ns * HE * 2);
    unsigned short* f_nj  = (unsigned short*)ws; ws = align256(ws + (size_t)Nd * HE * 2);
    unsigned short* h_src = (unsigned short*)ws; ws = align256(ws + (size_t)Ns * HN * 2);
    unsigned short* WT    = (unsigned short*)ws; ws = align256(ws + 49152 * 2);
    float* wsum    = (float*)ws; ws = align256(ws + HE * 4);
    int*   cnt     = (int*)ws;   ws = align256(ws + (size_t)Nd * 4);
    int*   cursor  = (int*)ws;   ws = align256(ws + (size_t)Nd * 4);
    int*   row_ptr = (int*)ws;   ws = align256(ws + (size_t)(Nd + 1) * 4);
    int*   partials= (int*)ws;   ws = align256(ws + 256 * 4);
    int2*  sr_s    = (int2*)ws;  ws = align256(ws + (size_t)E * 8);

    // cnt and cursor adjacent -> one memset
    hipMemsetAsync(cnt, 0, (size_t)((char*)row_ptr - (char*)cnt), stream);

    prep_hist<<<13 + (E + 255) / 256, 256, 0, stream>>>(
        W_fij, W_ni, W_ns, W_nj, dst, wsum, WT, cnt, E);

    int nb = (Nd + 1023) / 1024;
    scan1<<<nb, 256, 0, stream>>>(cnt, row_ptr, partials, Nd);
    scan2<<<1, 256, 0, stream>>>(partials, nb);

    int Mmax = (Ns > Nd) ? Ns : Nd;
    int nG = ((Mmax + 63) / 64) * 6;
    int nScatter = (E + 255) / 256;
    mega<<<nG + nScatter, 256, 0, stream>>>(
        nfeats, dst_feats, WT, b_ns, src, dst, reward, row_ptr, partials, cursor,
        f_ni, h_src, f_nj, sr_s, Ns, Nd, E, nG);

    fused_agg<<<(Nd + 3) / 4, 256, 0, stream>>>(
        f_ni, f_nj, h_src, sr_s, row_ptr, partials, wsum, b_e, attn, out, Nd, E);
}

// Round 11
// 310.737 us; speedup vs baseline: 1.5623x; 1.0258x over previous
//
#include <hip/hip_runtime.h>

#define IN_NODE 128
#define OUT_NODE 64
#define NHEAD 4
#define HN 256                 // NHEAD * OUT_NODE
#define HE 64                  // NHEAD * OUT_EDGE
#define LEAKY 0.01f
#define MAXD 96                // cached slots per wave in fused aggregate

typedef __attribute__((ext_vector_type(8))) short bf16x8;
typedef __attribute__((ext_vector_type(4))) float f32x4;

__device__ __forceinline__ float bf2f(unsigned short u) {
    union { unsigned u; float f; } v; v.u = ((unsigned)u) << 16; return v.f;
}
__device__ __forceinline__ unsigned short f2bf(float x) {
    union { float f; unsigned u; } v; v.f = x;
    unsigned r = v.u + 0x7FFF + ((v.u >> 16) & 1);   // RNE
    return (unsigned short)(r >> 16);
}
__device__ __forceinline__ bf16x8 cvt8(float4 a, float4 b) {
    bf16x8 r;
    r[0] = (short)f2bf(a.x); r[1] = (short)f2bf(a.y);
    r[2] = (short)f2bf(a.z); r[3] = (short)f2bf(a.w);
    r[4] = (short)f2bf(b.x); r[5] = (short)f2bf(b.y);
    r[6] = (short)f2bf(b.z); r[7] = (short)f2bf(b.w);
    return r;
}

// ------ prep: wsum (block 0) + W->WT bf16 transposes (blocks 1..12) + hist --
// WT layout: [0,8192) WT_ni[n][k] n<64; [8192,40960) WT_ns[n][k] n<256;
//            [40960,49152) WT_nj[n][k] n<64.   (k = 128)
__global__ void prep_hist(const float* __restrict__ W_fij,
                          const float* __restrict__ W_ni,
                          const float* __restrict__ W_ns,
                          const float* __restrict__ W_nj,
                          const int* __restrict__ dst,
                          float* __restrict__ wsum, unsigned short* __restrict__ WT,
                          int* __restrict__ cnt, int E) {
    int b = blockIdx.x;
    if (b == 0) {
        int k = threadIdx.x;
        if (k < 64) {
            float s = 0.f;
#pragma unroll
            for (int c = 0; c < 16; ++c) s += W_fij[c * 64 + k];
            wsum[k] = s;
        }
        return;
    }
    if (b <= 12) {
        int base = (b - 1) * 4096 + threadIdx.x;
#pragma unroll
        for (int i = 0; i < 16; ++i) {
            int idx = base + i * 256;
            unsigned short v;
            if (idx < 8192)      { int n = idx >> 7, k = idx & 127; v = f2bf(W_ni[k * 64 + n]); }
            else if (idx < 40960){ int j = idx - 8192;  int n = j >> 7, k = j & 127; v = f2bf(W_ns[k * 256 + n]); }
            else                 { int j = idx - 40960; int n = j >> 7, k = j & 127; v = f2bf(W_nj[k * 64 + n]); }
            WT[idx] = v;
        }
        return;
    }
    int i = (b - 13) * 256 + threadIdx.x;
    if (i < E) atomicAdd(&cnt[dst[i]], 1);
}

// ------- scan_all: full exclusive scan of cnt -> row_ptr, one dispatch ------
// nb (<=64) blocks, all co-resident. Each block scans its 1024-chunk, publishes
// its total (release flag), spin-waits all flags (acquire), offsets, writes.
__global__ __launch_bounds__(256) void scan_all(const int* __restrict__ cnt,
                                                int* __restrict__ row_ptr,
                                                int* __restrict__ partials,
                                                int* __restrict__ flags,
                                                int n, int E, int nb) {
    __shared__ int sums[256];
    __shared__ int s_base;
    int tid = threadIdx.x, b = blockIdx.x;
    int base = b * 1024;
    int v[4]; int tsum = 0;
#pragma unroll
    for (int j = 0; j < 4; ++j) {
        int idx = base + tid * 4 + j;
        v[j] = (idx < n) ? cnt[idx] : 0;
        tsum += v[j];
    }
    sums[tid] = tsum;
    __syncthreads();
    for (int off = 1; off < 256; off <<= 1) {
        int x = (tid >= off) ? sums[tid - off] : 0;
        __syncthreads();
        sums[tid] += x;
        __syncthreads();
    }
    if (tid == 255) {
        __hip_atomic_store(&partials[b], sums[255], __ATOMIC_RELAXED, __HIP_MEMORY_SCOPE_AGENT);
        __hip_atomic_store(&flags[b], 1, __ATOMIC_RELEASE, __HIP_MEMORY_SCOPE_AGENT);
    }
    if (tid < 64) {
        int val = 0;
        if (tid < nb) {
            while (__hip_atomic_load(&flags[tid], __ATOMIC_ACQUIRE, __HIP_MEMORY_SCOPE_AGENT) == 0) {
                __builtin_amdgcn_s_sleep(1);
            }
            val = __hip_atomic_load(&partials[tid], __ATOMIC_RELAXED, __HIP_MEMORY_SCOPE_AGENT);
        }
#pragma unroll
        for (int o = 1; o < 64; o <<= 1) {
            int x = __shfl_up(val, o);
            if (tid >= o) val += x;
        }
        int off = (b > 0) ? __shfl(val, b - 1) : 0;
        if (tid == 0) s_base = off;
    }
    __syncthreads();
    int run = s_base + sums[tid] - tsum;   // global exclusive prefix
#pragma unroll
    for (int j = 0; j < 4; ++j) {
        int idx = base + tid * 4 + j;
        if (idx < n) row_ptr[idx] = run;
        run += v[j];
    }
    if (b == nb - 1 && tid == 0) row_ptr[n] = E;
}

// ---------------- mega: gemm + scatter, STRIPED roles (3:2 per 5) -----------
// gemm idx gb: gy = gb % 6 (0->f_ni, 1..4->h_src slice, 5->f_nj), bx = gb / 6.
// scatter idx sb: edges [sb*256, ...), pos via countdown atomicSub on cnt.
__global__ __launch_bounds__(256) void mega(
    const float* __restrict__ nfeats, const float* __restrict__ dst_feats,
    const unsigned short* __restrict__ WT, const float* __restrict__ b_ns,
    const int* __restrict__ src, const int* __restrict__ dst,
    const float* __restrict__ reward, const int* __restrict__ row_ptr,
    int* __restrict__ cnt,
    unsigned short* __restrict__ f_ni, unsigned short* __restrict__ h_src,
    unsigned short* __restrict__ f_nj, int2* __restrict__ sr_s,
    int Ns, int Nd, int E, int nG, int nScatter)
{
    const int g = blockIdx.x / 5, r = blockIdx.x % 5;
    if (r < 3) {                                // ---- GEMM role ----
        const int gb = g * 3 + r;
        if (gb >= nG) return;
        const int gy = gb % 6;
        const int bx = gb / 6;
        const float* A; const unsigned short* wt; const float* bias = nullptr;
        unsigned short* C; int M, N, colBase;
        if (gy == 0)      { A = nfeats;    wt = WT;         C = f_ni;  M = Ns; N = 64;  colBase = 0; }
        else if (gy <= 4) { A = nfeats;    wt = WT + 8192;  C = h_src; M = Ns; N = 256; colBase = (gy - 1) * 64; bias = b_ns; }
        else              { A = dst_feats; wt = WT + 40960; C = f_nj;  M = Nd; N = 64;  colBase = 0; }

        const int w = threadIdx.x >> 6, lane = threadIdx.x & 63;
        const int rowW = bx * 64 + w * 16;
        if (rowW >= M) return;
        const int m = lane & 15, q = lane >> 4;
        int lrow = rowW + m; if (lrow >= M) lrow = M - 1;    // clamp (stores guarded)
        const float* arow = A + (size_t)lrow * 128 + q * 8;

        f32x4 acc0 = {}, acc1 = {}, acc2 = {}, acc3 = {};
#pragma unroll
        for (int kc = 0; kc < 128; kc += 32) {
            float4 a0 = *reinterpret_cast<const float4*>(arow + kc);
            float4 a1 = *reinterpret_cast<const float4*>(arow + kc + 4);
            bf16x8 af = cvt8(a0, a1);
            const unsigned short* bp = wt + (size_t)(colBase + m) * 128 + kc + q * 8;
            bf16x8 b0 = *reinterpret_cast<const bf16x8*>(bp);
            bf16x8 b1 = *reinterpret_cast<const bf16x8*>(bp + 16 * 128);
            bf16x8 b2 = *reinterpret_cast<const bf16x8*>(bp + 32 * 128);
            bf16x8 b3 = *reinterpret_cast<const bf16x8*>(bp + 48 * 128);
            acc0 = __builtin_amdgcn_mfma_f32_16x16x32_bf16(af, b0, acc0, 0, 0, 0);
            acc1 = __builtin_amdgcn_mfma_f32_16x16x32_bf16(af, b1, acc1, 0, 0, 0);
            acc2 = __builtin_amdgcn_mfma_f32_16x16x32_bf16(af, b2, acc2, 0, 0, 0);
            acc3 = __builtin_amdgcn_mfma_f32_16x16x32_bf16(af, b3, acc3, 0, 0, 0);
        }

#pragma unroll
        for (int f = 0; f < 4; ++f) {
            f32x4 a = (f == 0) ? acc0 : (f == 1) ? acc1 : (f == 2) ? acc2 : acc3;
            int col = colBase + f * 16 + m;
            float bv = bias ? bias[col] : 0.f;
#pragma unroll
            for (int rr = 0; rr < 4; ++rr) {
                int orow = rowW + q * 4 + rr;
                if (orow < M) C[(size_t)orow * N + col] = f2bf(a[rr] + bv);
            }
        }
        return;
    }
    // ---- scatter role ----
    const int sb = g * 2 + (r - 3);
    if (sb >= nScatter) return;
    int i = sb * 256 + threadIdx.x;
    if (i >= E) return;
    int d = dst[i];
    int pos = row_ptr[d] + atomicSub(&cnt[d], 1) - 1;
    sr_s[pos] = make_int2(src[i], __float_as_int(reward[i]));
}

// ------- fused logits + softmax + aggregation (R10 verbatim, row_ptr full) --
__global__ __launch_bounds__(256) void fused_agg(
    const unsigned short* __restrict__ f_ni, const unsigned short* __restrict__ f_nj,
    const unsigned short* __restrict__ h_src, const int2* __restrict__ sr_s,
    const int* __restrict__ row_ptr,
    const float* __restrict__ wsum, const float* __restrict__ b_e,
    const float* __restrict__ attn, float* __restrict__ out, int Nd)
{
    __shared__ float s_e[4][MAXD][4];
    __shared__ int   s_sn[4][MAXD];
    const int wv = threadIdx.x >> 6, lane = threadIdx.x & 63;
    const int d = blockIdx.x * 4 + wv;
    if (d >= Nd) return;
    const int l = lane & 15, sub = lane >> 4;
    const int beg = row_ptr[d];
    const int end = row_ptr[d + 1];

    for (int i = lane; i < MAXD; i += 64) s_sn[wv][i] = -1;  // sentinel pad

    ushort4 uj = *reinterpret_cast<const ushort4*>(f_nj + (size_t)d * HE + 4 * l);
    float4 fnj = { bf2f(uj.x), bf2f(uj.y), bf2f(uj.z), bf2f(uj.w) };
    float4 ws = *reinterpret_cast<const float4*>(wsum + 4 * l);
    float4 be = *reinterpret_cast<const float4*>(b_e + 4 * l);
    float4 at = *reinterpret_cast<const float4*>(attn + 4 * l);

    float den = 0.f;
    for (int base = beg; base < end; base += 4) {
        int slot = base + sub;
        if (slot < end) {
            int2 sr = sr_s[slot];
            int sn = sr.x;
            float r = __int_as_float(sr.y);
            ushort4 ui = *reinterpret_cast<const ushort4*>(f_ni + (size_t)sn * HE + 4 * l);
            float t, v;
            v = bf2f(ui.x) + fnj.x + r * ws.x + be.x; v = (v >= 0.f) ? v : LEAKY * v; t  = v * at.x;
            v = bf2f(ui.y) + fnj.y + r * ws.y + be.y; v = (v >= 0.f) ? v : LEAKY * v; t += v * at.y;
            v = bf2f(ui.z) + fnj.z + r * ws.z + be.z; v = (v >= 0.f) ? v : LEAKY * v; t += v * at.z;
            v = bf2f(ui.w) + fnj.w + r * ws.w + be.w; v = (v >= 0.f) ? v : LEAKY * v; t += v * at.w;
            t += __shfl_xor(t, 1);
            t += __shfl_xor(t, 2);          // lanes 4h..4h+3 of subgroup hold head h logit
            float ev = __expf(t);
            den += ev;
            int idx = slot - beg;
            if (idx < MAXD) {
                if ((l & 3) == 0) s_e[wv][idx][l >> 2] = ev;
                if (l == 0) s_sn[wv][idx] = sn;
            }
        }
    }
    den += __shfl_xor(den, 16);
    den += __shfl_xor(den, 32);             // total for head (l>>2), all subgroups
    float dh = __shfl(den, (lane >> 4) << 2);   // head lane>>4's denominator
    float invh = (dh > 0.f) ? 1.f / dh : 0.f;
    const int h = lane >> 4;

    float a0 = 0.f, a1 = 0.f, a2 = 0.f, a3 = 0.f;
    int cap = min(end - beg, MAXD);
    int npad = (cap + 7) & ~7;
    for (int idx0 = 0; idx0 < npad; idx0 += 8) {
#pragma unroll
        for (int j = 0; j < 8; ++j) {
            int idx = idx0 + j;
            int sn = s_sn[wv][idx];
            float wgt = (sn >= 0) ? s_e[wv][idx][h] * invh : 0.f;
            int sa = (sn >= 0) ? sn : 0;
            ushort4 u = *reinterpret_cast<const ushort4*>(h_src + (size_t)sa * HN + lane * 4);
            a0 = fmaf(wgt, bf2f(u.x), a0);
            a1 = fmaf(wgt, bf2f(u.y), a1);
            a2 = fmaf(wgt, bf2f(u.z), a2);
            a3 = fmaf(wgt, bf2f(u.w), a3);
        }
    }
    // overflow tail (degree > MAXD): recompute logits serially (cold path)
    for (int slot = beg + MAXD; slot < end; ++slot) {
        int2 sr = sr_s[slot];
        int sn = sr.x;
        float r = __int_as_float(sr.y);
        float v = bf2f(f_ni[(size_t)sn * HE + lane]) + bf2f(f_nj[(size_t)d * HE + lane])
                + r * wsum[lane] + b_e[lane];
        v = (v >= 0.f) ? v : LEAKY * v;
        float t = v * attn[lane];
        t += __shfl_xor(t, 1);
        t += __shfl_xor(t, 2);
        t += __shfl_xor(t, 4);
        t += __shfl_xor(t, 8);
        float wgt = __expf(t) * invh;
        ushort4 u = *reinterpret_cast<const ushort4*>(h_src + (size_t)sn * HN + lane * 4);
        a0 = fmaf(wgt, bf2f(u.x), a0);
        a1 = fmaf(wgt, bf2f(u.y), a1);
        a2 = fmaf(wgt, bf2f(u.z), a2);
        a3 = fmaf(wgt, bf2f(u.w), a3);
    }

    a0 += __shfl_xor(a0, 16); a0 += __shfl_xor(a0, 32);
    a1 += __shfl_xor(a1, 16); a1 += __shfl_xor(a1, 32);
    a2 += __shfl_xor(a2, 16); a2 += __shfl_xor(a2, 32);
    a3 += __shfl_xor(a3, 16); a3 += __shfl_xor(a3, 32);
    if (lane < 16) {
        float4 o = { fmaxf(a0 * 0.25f, 0.f), fmaxf(a1 * 0.25f, 0.f),
                     fmaxf(a2 * 0.25f, 0.f), fmaxf(a3 * 0.25f, 0.f) };
        *reinterpret_cast<float4*>(out + (size_t)d * OUT_NODE + lane * 4) = o;
    }
}

static inline char* align256(char* p) {
    return (char*)(((uintptr_t)p + 255) & ~(uintptr_t)255);
}

extern "C" void kernel_launch(void* const* d_in, const int* in_sizes, int n_in,
                              void* d_out, int out_size, void* d_ws, size_t ws_size,
                              hipStream_t stream) {
    const float* nfeats    = (const float*)d_in[0];
    const float* dst_feats = (const float*)d_in[1];
    const float* reward    = (const float*)d_in[2];
    const int*   src       = (const int*)d_in[3];
    const int*   dst       = (const int*)d_in[4];
    const float* W_ns      = (const float*)d_in[5];
    const float* b_ns      = (const float*)d_in[6];
    const float* W_ni      = (const float*)d_in[7];
    const float* W_nj      = (const float*)d_in[8];
    const float* W_fij     = (const float*)d_in[9];
    const float* attn      = (const float*)d_in[10];
    const float* b_e       = (const float*)d_in[11];
    float* out = (float*)d_out;

    const int Ns = in_sizes[0] / IN_NODE;
    const int Nd = in_sizes[1] / IN_NODE;
    const int E  = in_sizes[2];

    char* ws = (char*)d_ws;
    unsigned short* f_ni  = (unsigned short*)ws; ws = align256(ws + (size_t)Ns * HE * 2);
    unsigned short* f_nj  = (unsigned short*)ws; ws = align256(ws + (size_t)Nd * HE * 2);
    unsigned short* h_src = (unsigned short*)ws; ws = align256(ws + (size_t)Ns * HN * 2);
    unsigned short* WT    = (unsigned short*)ws; ws = align256(ws + 49152 * 2);
    float* wsum    = (float*)ws; ws = align256(ws + HE * 4);
    int*   cnt     = (int*)ws;   // cnt + flags zeroed by one memset
    int*   flags   = cnt + Nd;   ws = align256(ws + (size_t)(Nd + 64) * 4);
    int*   row_ptr = (int*)ws;   ws = align256(ws + (size_t)(Nd + 1) * 4);
    int*   partials= (int*)ws;   ws = align256(ws + 256 * 4);
    int2*  sr_s    = (int2*)ws;  ws = align256(ws + (size_t)E * 8);

    hipMemsetAsync(cnt, 0, (size_t)(Nd + 64) * 4, stream);

    prep_hist<<<13 + (E + 255) / 256, 256, 0, stream>>>(
        W_fij, W_ni, W_ns, W_nj, dst, wsum, WT, cnt, E);

    int nb = (Nd + 1023) / 1024;
    scan_all<<<nb, 256, 0, stream>>>(cnt, row_ptr, partials, flags, Nd, E, nb);

    int Mmax = (Ns > Nd) ? Ns : Nd;
    int nG = ((Mmax + 63) / 64) * 6;
    int nScatter = (E + 255) / 256;
    int nGroups = ((nG + 2) / 3 > (nScatter + 1) / 2) ? (nG + 2) / 3 : (nScatter + 1) / 2;
    mega<<<nGroups * 5, 256, 0, stream>>>(
        nfeats, dst_feats, WT, b_ns, src, dst, reward, row_ptr, cnt,
        f_ni, h_src, f_nj, sr_s, Ns, Nd, E, nG, nScatter);

    fused_agg<<<(Nd + 3) / 4, 256, 0, stream>>>(
        f_ni, f_nj, h_src, sr_s, row_ptr, wsum, b_e, attn, out, Nd);
}